// Round 1
// baseline (717.170 us; speedup 1.0000x reference)
//
#include <hip/hip_runtime.h>

#define D 256

// ---------------- setup kernels ----------------

__global__ void init_kernel(int* __restrict__ deg, int* __restrict__ cursor, int n) {
    int i = blockIdx.x * blockDim.x + threadIdx.x;
    if (i < n) { deg[i] = 1; cursor[i] = 0; }   // deg starts at 1 (self-loop)
}

__global__ void hist_kernel(const int* __restrict__ dst, int* __restrict__ deg, int e) {
    int i = blockIdx.x * blockDim.x + threadIdx.x;
    if (i < e) atomicAdd(&deg[dst[i]], 1);
}

__global__ void dinv_kernel(const int* __restrict__ deg, float* __restrict__ dinv, int n) {
    int i = blockIdx.x * blockDim.x + threadIdx.x;
    if (i < n) dinv[i] = rsqrtf((float)deg[i]);  // deg >= 1 always
}

// single-block exclusive scan of in-degrees (deg[i]-1) -> rowptr[0..n]
__global__ void scan_kernel(const int* __restrict__ deg, int* __restrict__ rowptr, int n) {
    __shared__ int sums[256];
    int t = threadIdx.x;
    int chunk = (n + 255) / 256;
    int lo = t * chunk;
    int hi = lo + chunk; if (hi > n) hi = n; if (lo > n) lo = n;
    int s = 0;
    for (int i = lo; i < hi; ++i) s += deg[i] - 1;
    sums[t] = s;
    __syncthreads();
    for (int off = 1; off < 256; off <<= 1) {
        int v = (t >= off) ? sums[t - off] : 0;
        __syncthreads();
        sums[t] += v;
        __syncthreads();
    }
    int pre = (t == 0) ? 0 : sums[t - 1];
    for (int i = lo; i < hi; ++i) { rowptr[i] = pre; pre += deg[i] - 1; }
    if (t == 255) rowptr[n] = pre;
}

__global__ void fill_kernel(const int* __restrict__ src, const int* __restrict__ dst,
                            const int* __restrict__ rowptr, int* __restrict__ cursor,
                            int* __restrict__ csr, int e) {
    int i = blockIdx.x * blockDim.x + threadIdx.x;
    if (i < e) {
        int d = dst[i];
        int p = atomicAdd(&cursor[d], 1);
        csr[rowptr[d] + p] = src[i];
    }
}

// ---------------- GEMM: C = op(A @ B) ----------------
// A: [M, 256] row-major, B: [256, 256] row-major, C: [M, 256]
// mode 0: C = relu(A@B + bias[col])
// mode 1: C = (A@B) * dinv[row]
__global__ __launch_bounds__(256) void gemm_kernel(
    const float* __restrict__ A, const float* __restrict__ B,
    const float* __restrict__ bias, const float* __restrict__ dinv,
    float* __restrict__ C, int M, int mode)
{
    __shared__ float As[16][132];   // [k][m], padded to break bank conflicts
    __shared__ float Bs[16][132];   // [k][n]
    const int tid = threadIdx.x;
    const int tx = tid & 15, ty = tid >> 4;
    const int row0 = blockIdx.y * 128;
    const int col0 = blockIdx.x * 128;

    float acc[8][8];
#pragma unroll
    for (int i = 0; i < 8; ++i)
#pragma unroll
        for (int j = 0; j < 8; ++j) acc[i][j] = 0.f;

    for (int k0 = 0; k0 < D; k0 += 16) {
        // A tile 128x16 -> As transposed
#pragma unroll
        for (int i = 0; i < 2; ++i) {
            int idx = i * 256 + tid;
            int r = idx >> 2;            // 0..127
            int c4 = (idx & 3) * 4;      // 0,4,8,12
            float4 v = make_float4(0.f, 0.f, 0.f, 0.f);
            int grow = row0 + r;
            if (grow < M) v = *reinterpret_cast<const float4*>(&A[(size_t)grow * D + k0 + c4]);
            As[c4 + 0][r] = v.x; As[c4 + 1][r] = v.y;
            As[c4 + 2][r] = v.z; As[c4 + 3][r] = v.w;
        }
        // B tile 16x128 -> Bs direct
#pragma unroll
        for (int i = 0; i < 2; ++i) {
            int idx = i * 256 + tid;
            int r = idx >> 5;            // 0..15
            int c4 = (idx & 31) * 4;     // 0..124
            float4 v = *reinterpret_cast<const float4*>(&B[(size_t)(k0 + r) * D + col0 + c4]);
            *reinterpret_cast<float4*>(&Bs[r][c4]) = v;
        }
        __syncthreads();
#pragma unroll
        for (int k = 0; k < 16; ++k) {
            float a[8], b[8];
            *(float4*)&a[0] = *(float4*)&As[k][ty * 8];
            *(float4*)&a[4] = *(float4*)&As[k][ty * 8 + 4];
            *(float4*)&b[0] = *(float4*)&Bs[k][tx * 8];
            *(float4*)&b[4] = *(float4*)&Bs[k][tx * 8 + 4];
#pragma unroll
            for (int i = 0; i < 8; ++i)
#pragma unroll
                for (int j = 0; j < 8; ++j) acc[i][j] += a[i] * b[j];
        }
        __syncthreads();
    }

#pragma unroll
    for (int i = 0; i < 8; ++i) {
        int grow = row0 + ty * 8 + i;
        if (grow >= M) continue;
        float scale = (mode == 1) ? dinv[grow] : 1.f;
#pragma unroll
        for (int j = 0; j < 8; j += 4) {
            int gcol = col0 + tx * 8 + j;
            float4 v;
            v.x = acc[i][j + 0]; v.y = acc[i][j + 1];
            v.z = acc[i][j + 2]; v.w = acc[i][j + 3];
            if (mode == 0) {
                v.x = fmaxf(v.x + bias[gcol + 0], 0.f);
                v.y = fmaxf(v.y + bias[gcol + 1], 0.f);
                v.z = fmaxf(v.z + bias[gcol + 2], 0.f);
                v.w = fmaxf(v.w + bias[gcol + 3], 0.f);
            } else {
                v.x *= scale; v.y *= scale; v.z *= scale; v.w *= scale;
            }
            *reinterpret_cast<float4*>(&C[(size_t)grow * D + gcol]) = v;
        }
    }
}

// ---------------- aggregation ----------------
// out[d] = relu(dinv[d] * (hn[d] + sum_{s in in(d)} hn[s]) + bias[col])
// one wave per node, lane handles 4 contiguous floats of the 256-wide row
__global__ __launch_bounds__(256) void agg_kernel(
    const float* __restrict__ hn, const int* __restrict__ rowptr,
    const int* __restrict__ csr, const float* __restrict__ dinv,
    const float* __restrict__ bias, float* __restrict__ out, int n)
{
    int wave = threadIdx.x >> 6;
    int lane = threadIdx.x & 63;
    int node = blockIdx.x * 4 + wave;
    if (node >= n) return;
    int c = lane * 4;
    float4 acc = *reinterpret_cast<const float4*>(&hn[(size_t)node * D + c]);  // self loop
    int e0 = rowptr[node], e1 = rowptr[node + 1];
    for (int e = e0; e < e1; ++e) {
        int s = csr[e];
        float4 v = *reinterpret_cast<const float4*>(&hn[(size_t)s * D + c]);
        acc.x += v.x; acc.y += v.y; acc.z += v.z; acc.w += v.w;
    }
    float di = dinv[node];
    float4 b = *reinterpret_cast<const float4*>(&bias[c]);
    float4 o;
    o.x = fmaxf(acc.x * di + b.x, 0.f);
    o.y = fmaxf(acc.y * di + b.y, 0.f);
    o.z = fmaxf(acc.z * di + b.z, 0.f);
    o.w = fmaxf(acc.w * di + b.w, 0.f);
    *reinterpret_cast<float4*>(&out[(size_t)node * D + c]) = o;
}

// ---------------- launch ----------------

extern "C" void kernel_launch(void* const* d_in, const int* in_sizes, int n_in,
                              void* d_out, int out_size, void* d_ws, size_t ws_size,
                              hipStream_t stream) {
    const float* input  = (const float*)d_in[0];
    const int*   edge   = (const int*)d_in[1];
    const float* weight = (const float*)d_in[2];
    const float* bias   = (const float*)d_in[3];
    const float* conv_w = (const float*)d_in[4];
    const float* conv_b = (const float*)d_in[5];
    float* out = (float*)d_out;

    const int n = in_sizes[0] / D;     // 50000
    const int E = in_sizes[1] / 2;     // 800000
    const int* src = edge;
    const int* dst = edge + E;

    char* ws = (char*)d_ws;
    size_t off = 0;
    auto alloc = [&](size_t bytes) -> void* {
        void* p = ws + off;
        off = (off + bytes + 255) & ~(size_t)255;
        return p;
    };
    float* buf0   = (float*)alloc((size_t)n * D * sizeof(float));
    float* buf1   = (float*)alloc((size_t)n * D * sizeof(float));
    int*   deg    = (int*)alloc((size_t)n * sizeof(int));
    int*   cursor = (int*)alloc((size_t)n * sizeof(int));
    float* dinv   = (float*)alloc((size_t)n * sizeof(float));
    int*   rowptr = (int*)alloc((size_t)(n + 1) * sizeof(int));
    int*   csr    = (int*)alloc((size_t)E * sizeof(int));

    int nb = (n + 255) / 256;
    int eb = (E + 255) / 256;
    init_kernel<<<nb, 256, 0, stream>>>(deg, cursor, n);
    hist_kernel<<<eb, 256, 0, stream>>>(dst, deg, E);
    dinv_kernel<<<nb, 256, 0, stream>>>(deg, dinv, n);
    scan_kernel<<<1, 256, 0, stream>>>(deg, rowptr, n);
    fill_kernel<<<eb, 256, 0, stream>>>(src, dst, rowptr, cursor, csr, E);

    dim3 ggrid(D / 128, (n + 127) / 128);
    // x1 = relu(input @ weight + bias)
    gemm_kernel<<<ggrid, 256, 0, stream>>>(input, weight, bias, dinv, buf0, n, 0);
    // layer 0: hn = (x1 @ W0) * dinv[row]
    gemm_kernel<<<ggrid, 256, 0, stream>>>(buf0, conv_w, nullptr, dinv, buf1, n, 1);
    // x2 = relu(dinv * (agg hn) + b0)
    agg_kernel<<<(n + 3) / 4, 256, 0, stream>>>(buf1, rowptr, csr, dinv, conv_b, buf0, n);
    // layer 1: hn2 = (x2 @ W1) * dinv[row]
    gemm_kernel<<<ggrid, 256, 0, stream>>>(buf0, conv_w + D * D, nullptr, dinv, buf1, n, 1);
    // out = relu(dinv * (agg hn2) + b1)
    agg_kernel<<<(n + 3) / 4, 256, 0, stream>>>(buf1, rowptr, csr, dinv, conv_b + D, out, n);
}

// Round 2
// 485.570 us; speedup vs baseline: 1.4770x; 1.4770x over previous
//
#include <hip/hip_runtime.h>

#define D 256
typedef unsigned short u16;
typedef __attribute__((ext_vector_type(8))) short bf16x8;
typedef __attribute__((ext_vector_type(4))) float f32x4;

__device__ __forceinline__ float bf2f(u16 u) {
    union { unsigned int i; float f; } x; x.i = ((unsigned int)u) << 16; return x.f;
}
__device__ __forceinline__ u16 f2bf(float f) {
    union { float f; unsigned int i; } x; x.f = f;
    unsigned int r = x.i + 0x7fff + ((x.i >> 16) & 1);   // RNE
    return (u16)(r >> 16);
}
__device__ __forceinline__ void gload16(const void* g, void* l) {
    __builtin_amdgcn_global_load_lds(
        (const __attribute__((address_space(1))) void*)g,
        (__attribute__((address_space(3))) void*)l, 16, 0, 0);
}

// ---------------- setup kernels ----------------

__global__ void init_kernel(int* __restrict__ deg, int* __restrict__ cursor, int n) {
    int i = blockIdx.x * blockDim.x + threadIdx.x;
    if (i < n) { deg[i] = 1; cursor[i] = 0; }   // deg starts at 1 (self-loop)
}

__global__ void hist_kernel(const int* __restrict__ dst, int* __restrict__ deg, int e) {
    int i = blockIdx.x * blockDim.x + threadIdx.x;
    if (i < e) atomicAdd(&deg[dst[i]], 1);
}

__global__ void dinv_kernel(const int* __restrict__ deg, float* __restrict__ dinv, int n) {
    int i = blockIdx.x * blockDim.x + threadIdx.x;
    if (i < n) dinv[i] = rsqrtf((float)deg[i]);
}

// single-block exclusive scan of in-degrees (deg[i]-1) -> rowptr[0..n]
__global__ void scan_kernel(const int* __restrict__ deg, int* __restrict__ rowptr, int n) {
    __shared__ int sums[256];
    int t = threadIdx.x;
    int chunk = (n + 255) / 256;
    int lo = t * chunk;
    int hi = lo + chunk; if (hi > n) hi = n; if (lo > n) lo = n;
    int s = 0;
    for (int i = lo; i < hi; ++i) s += deg[i] - 1;
    sums[t] = s;
    __syncthreads();
    for (int off = 1; off < 256; off <<= 1) {
        int v = (t >= off) ? sums[t - off] : 0;
        __syncthreads();
        sums[t] += v;
        __syncthreads();
    }
    int pre = (t == 0) ? 0 : sums[t - 1];
    for (int i = lo; i < hi; ++i) { rowptr[i] = pre; pre += deg[i] - 1; }
    if (t == 255) rowptr[n] = pre;
}

__global__ void fill_kernel(const int* __restrict__ src, const int* __restrict__ dst,
                            const int* __restrict__ rowptr, int* __restrict__ cursor,
                            int* __restrict__ csr, int e) {
    int i = blockIdx.x * blockDim.x + threadIdx.x;
    if (i < e) {
        int d = dst[i];
        int p = atomicAdd(&cursor[d], 1);
        csr[rowptr[d] + p] = src[i];
    }
}

// ---------------- conversions ----------------

// f32 -> bf16, 4 elems/thread
__global__ void cvt_kernel(const float* __restrict__ in, u16* __restrict__ out, int n4) {
    int i = blockIdx.x * blockDim.x + threadIdx.x;
    if (i < n4) {
        float4 v = *reinterpret_cast<const float4*>(&in[(size_t)i * 4]);
        ushort4 o;
        o.x = f2bf(v.x); o.y = f2bf(v.y); o.z = f2bf(v.z); o.w = f2bf(v.w);
        *reinterpret_cast<ushort4*>(&out[(size_t)i * 4]) = o;
    }
}

// W [K=256][N=256] f32 -> Wt [N][K] bf16 (transpose + convert)
__global__ __launch_bounds__(256) void transpose_cvt_kernel(
    const float* __restrict__ W, u16* __restrict__ Wt) {
    __shared__ float t[32][33];
    int bx = blockIdx.x * 32, by = blockIdx.y * 32;   // bx: K base, by: N base
    int tx = threadIdx.x & 31, ty = threadIdx.x >> 5; // 32x8
#pragma unroll
    for (int i = 0; i < 32; i += 8)
        t[ty + i][tx] = W[(size_t)(bx + ty + i) * D + by + tx];
    __syncthreads();
#pragma unroll
    for (int i = 0; i < 32; i += 8)
        Wt[(size_t)(by + ty + i) * D + bx + tx] = f2bf(t[tx][ty + i]);
}

// ---------------- bf16 MFMA GEMM ----------------
// A: [M][256] bf16 row-major; Bt: [256][256] bf16, Bt[n][k] (B transposed)
// mode 0: C = relu(A@B + bias[col]) -> bf16
// mode 1: C = (A@B) * dinv[row]     -> bf16
// tile 128x128, BK=32, 4 waves (2x2), each wave 64x64 = 4x4 frags of 16x16x32
__global__ __launch_bounds__(256) void mfma_gemm(
    const u16* __restrict__ A, const u16* __restrict__ Bt,
    const float* __restrict__ bias, const float* __restrict__ dinv,
    u16* __restrict__ C, int M, int mode)
{
    __shared__ u16 As[128 * 32];
    __shared__ u16 Bs[128 * 32];
    const int tid = threadIdx.x;
    const int lane = tid & 63;
    const int wave = tid >> 6;
    const int wr = wave >> 1, wc = wave & 1;
    const int row0 = blockIdx.y * 128, col0 = blockIdx.x * 128;
    const int l16 = lane & 15, kg = lane >> 4;

    f32x4 acc[4][4] = {};

    for (int k0 = 0; k0 < D; k0 += 32) {
        // stage A[128][32] and Bt[128][32] tiles; LDS linear, source pre-swizzled
        // swizzle: LDS slot (row, c) holds global chunk c ^ ((row>>1)&3)
#pragma unroll
        for (int i = 0; i < 2; ++i) {
            int idx = i * 256 + tid;
            int r = idx >> 2, c = idx & 3;
            int csw = c ^ ((r >> 1) & 3);
            char* ldsbase_a = (char*)As + ((i * 256 + (tid & ~63)) << 4);
            char* ldsbase_b = (char*)Bs + ((i * 256 + (tid & ~63)) << 4);
            int grow = row0 + r; if (grow >= M) grow = M - 1;
            gload16(&A[(size_t)grow * D + k0 + csw * 8], ldsbase_a);
            gload16(&Bt[(size_t)(col0 + r) * D + k0 + csw * 8], ldsbase_b);
        }
        __syncthreads();
        bf16x8 af[4], bfr[4];
        int ksw = kg ^ ((l16 >> 1) & 3);   // inverse swizzle on read
#pragma unroll
        for (int m = 0; m < 4; ++m) {
            int row = wr * 64 + m * 16 + l16;
            af[m] = *reinterpret_cast<const bf16x8*>(&As[row * 32 + ksw * 8]);
        }
#pragma unroll
        for (int nn = 0; nn < 4; ++nn) {
            int row = wc * 64 + nn * 16 + l16;
            bfr[nn] = *reinterpret_cast<const bf16x8*>(&Bs[row * 32 + ksw * 8]);
        }
#pragma unroll
        for (int m = 0; m < 4; ++m)
#pragma unroll
            for (int nn = 0; nn < 4; ++nn)
                acc[m][nn] = __builtin_amdgcn_mfma_f32_16x16x32_bf16(
                    af[m], bfr[nn], acc[m][nn], 0, 0, 0);
        __syncthreads();
    }

    // epilogue: C/D layout col = lane&15, row = (lane>>4)*4 + reg
#pragma unroll
    for (int m = 0; m < 4; ++m) {
#pragma unroll
        for (int nn = 0; nn < 4; ++nn) {
            int gcol = col0 + wc * 64 + nn * 16 + l16;
#pragma unroll
            for (int j = 0; j < 4; ++j) {
                int grow = row0 + wr * 64 + m * 16 + kg * 4 + j;
                if (grow >= M) continue;
                float v = acc[m][nn][j];
                if (mode == 0) v = fmaxf(v + bias[gcol], 0.f);
                else           v *= dinv[grow];
                C[(size_t)grow * D + gcol] = f2bf(v);
            }
        }
    }
}

// ---------------- aggregation (bf16 gather, f32 accum) ----------------
// out[d] = relu(dinv[d] * (hn[d] + sum_{s in in(d)} hn[s]) + bias[col])
// one wave per node; lane handles 4 bf16 columns (8B loads)
__global__ __launch_bounds__(256) void agg_kernel(
    const u16* __restrict__ hn, const int* __restrict__ rowptr,
    const int* __restrict__ csr, const float* __restrict__ dinv,
    const float* __restrict__ bias,
    u16* __restrict__ out_bf, float* __restrict__ out_f32, int n)
{
    int wave = threadIdx.x >> 6;
    int lane = threadIdx.x & 63;
    int node = blockIdx.x * 4 + wave;
    if (node >= n) return;
    int c = lane * 4;
    ushort4 sv = *reinterpret_cast<const ushort4*>(&hn[(size_t)node * D + c]);
    float a0 = bf2f(sv.x), a1 = bf2f(sv.y), a2 = bf2f(sv.z), a3 = bf2f(sv.w);
    int e0 = rowptr[node], e1 = rowptr[node + 1];
    for (int e = e0; e < e1; ++e) {
        int s = csr[e];
        ushort4 v = *reinterpret_cast<const ushort4*>(&hn[(size_t)s * D + c]);
        a0 += bf2f(v.x); a1 += bf2f(v.y); a2 += bf2f(v.z); a3 += bf2f(v.w);
    }
    float di = dinv[node];
    float4 b = *reinterpret_cast<const float4*>(&bias[c]);
    a0 = fmaxf(a0 * di + b.x, 0.f);
    a1 = fmaxf(a1 * di + b.y, 0.f);
    a2 = fmaxf(a2 * di + b.z, 0.f);
    a3 = fmaxf(a3 * di + b.w, 0.f);
    if (out_bf) {
        ushort4 o; o.x = f2bf(a0); o.y = f2bf(a1); o.z = f2bf(a2); o.w = f2bf(a3);
        *reinterpret_cast<ushort4*>(&out_bf[(size_t)node * D + c]) = o;
    } else {
        float4 o; o.x = a0; o.y = a1; o.z = a2; o.w = a3;
        *reinterpret_cast<float4*>(&out_f32[(size_t)node * D + c]) = o;
    }
}

// ---------------- launch ----------------

extern "C" void kernel_launch(void* const* d_in, const int* in_sizes, int n_in,
                              void* d_out, int out_size, void* d_ws, size_t ws_size,
                              hipStream_t stream) {
    const float* input  = (const float*)d_in[0];
    const int*   edge   = (const int*)d_in[1];
    const float* weight = (const float*)d_in[2];
    const float* bias   = (const float*)d_in[3];
    const float* conv_w = (const float*)d_in[4];
    const float* conv_b = (const float*)d_in[5];
    float* out = (float*)d_out;

    const int n = in_sizes[0] / D;     // 50000
    const int E = in_sizes[1] / 2;     // 800000
    const int* src = edge;
    const int* dst = edge + E;

    char* ws = (char*)d_ws;
    size_t off = 0;
    auto alloc = [&](size_t bytes) -> void* {
        void* p = ws + off;
        off = (off + bytes + 255) & ~(size_t)255;
        return p;
    };
    u16*   Ain    = (u16*)alloc((size_t)n * D * sizeof(u16));
    u16*   bufA   = (u16*)alloc((size_t)n * D * sizeof(u16));
    u16*   bufB   = (u16*)alloc((size_t)n * D * sizeof(u16));
    u16*   Wt     = (u16*)alloc((size_t)3 * D * D * sizeof(u16));  // weight, W0, W1
    int*   deg    = (int*)alloc((size_t)n * sizeof(int));
    int*   cursor = (int*)alloc((size_t)n * sizeof(int));
    float* dinv   = (float*)alloc((size_t)n * sizeof(float));
    int*   rowptr = (int*)alloc((size_t)(n + 1) * sizeof(int));
    int*   csr    = (int*)alloc((size_t)E * sizeof(int));

    int nb = (n + 255) / 256;
    int eb = (E + 255) / 256;
    init_kernel<<<nb, 256, 0, stream>>>(deg, cursor, n);
    hist_kernel<<<eb, 256, 0, stream>>>(dst, deg, E);
    dinv_kernel<<<nb, 256, 0, stream>>>(deg, dinv, n);
    scan_kernel<<<1, 256, 0, stream>>>(deg, rowptr, n);
    fill_kernel<<<eb, 256, 0, stream>>>(src, dst, rowptr, cursor, csr, E);

    // conversions
    int n4 = n * D / 4;
    cvt_kernel<<<(n4 + 255) / 256, 256, 0, stream>>>(input, Ain, n4);
    dim3 tgrid(8, 8);
    transpose_cvt_kernel<<<tgrid, 256, 0, stream>>>(weight, Wt);
    transpose_cvt_kernel<<<tgrid, 256, 0, stream>>>(conv_w, Wt + D * D);
    transpose_cvt_kernel<<<tgrid, 256, 0, stream>>>(conv_w + D * D, Wt + 2 * D * D);

    dim3 ggrid(D / 128, (n + 127) / 128);
    // x1 = relu(input @ W + b)          -> bufA (bf16)
    mfma_gemm<<<ggrid, 256, 0, stream>>>(Ain, Wt, bias, dinv, bufA, n, 0);
    // hn = (x1 @ W0) * dinv[row]        -> bufB (bf16)
    mfma_gemm<<<ggrid, 256, 0, stream>>>(bufA, Wt + D * D, nullptr, dinv, bufB, n, 1);
    // x2 = relu(dinv * agg(hn) + b0)    -> bufA (bf16)
    agg_kernel<<<(n + 3) / 4, 256, 0, stream>>>(bufB, rowptr, csr, dinv, conv_b, bufA, nullptr, n);
    // hn2 = (x2 @ W1) * dinv[row]       -> bufB (bf16)
    mfma_gemm<<<ggrid, 256, 0, stream>>>(bufA, Wt + 2 * D * D, nullptr, dinv, bufB, n, 1);
    // out = relu(dinv * agg(hn2) + b1)  -> out (f32)
    agg_kernel<<<(n + 3) / 4, 256, 0, stream>>>(bufB, rowptr, csr, dinv, conv_b + D, nullptr, out, n);
}

// Round 3
// 424.150 us; speedup vs baseline: 1.6908x; 1.1448x over previous
//
#include <hip/hip_runtime.h>

#define D 256
typedef unsigned short u16;
typedef __attribute__((ext_vector_type(8))) short bf16x8;
typedef __attribute__((ext_vector_type(4))) float f32x4;

__device__ __forceinline__ float bf2f(u16 u) {
    union { unsigned int i; float f; } x; x.i = ((unsigned int)u) << 16; return x.f;
}
__device__ __forceinline__ u16 f2bf(float f) {
    union { float f; unsigned int i; } x; x.f = f;
    unsigned int r = x.i + 0x7fff + ((x.i >> 16) & 1);   // RNE
    return (u16)(r >> 16);
}
__device__ __forceinline__ void gload16(const void* g, void* l) {
    __builtin_amdgcn_global_load_lds(
        (const __attribute__((address_space(1))) void*)g,
        (__attribute__((address_space(3))) void*)l, 16, 0, 0);
}

// ---------------- setup kernels ----------------

__global__ void init_kernel(int* __restrict__ deg, int* __restrict__ cursor, int n) {
    int i = blockIdx.x * blockDim.x + threadIdx.x;
    if (i < n) { deg[i] = 1; cursor[i] = 0; }   // deg starts at 1 (self-loop)
}

__global__ void hist_kernel(const int* __restrict__ dst, int* __restrict__ deg, int e) {
    int i = blockIdx.x * blockDim.x + threadIdx.x;
    int b = i * 4;
    if (b + 3 < e) {
        int4 v = *reinterpret_cast<const int4*>(&dst[b]);
        atomicAdd(&deg[v.x], 1); atomicAdd(&deg[v.y], 1);
        atomicAdd(&deg[v.z], 1); atomicAdd(&deg[v.w], 1);
    } else {
        for (int j = b; j < e; ++j) atomicAdd(&deg[dst[j]], 1);
    }
}

__global__ void dinv_kernel(const int* __restrict__ deg, float* __restrict__ dinv, int n) {
    int i = blockIdx.x * blockDim.x + threadIdx.x;
    if (i < n) dinv[i] = rsqrtf((float)deg[i]);
}

// single-block exclusive scan of in-degrees (deg[i]-1) -> rowptr[0..n]
__global__ void scan_kernel(const int* __restrict__ deg, int* __restrict__ rowptr, int n) {
    __shared__ int sums[256];
    int t = threadIdx.x;
    int chunk = (n + 255) / 256;
    int lo = t * chunk;
    int hi = lo + chunk; if (hi > n) hi = n; if (lo > n) lo = n;
    int s = 0;
    for (int i = lo; i < hi; ++i) s += deg[i] - 1;
    sums[t] = s;
    __syncthreads();
    for (int off = 1; off < 256; off <<= 1) {
        int v = (t >= off) ? sums[t - off] : 0;
        __syncthreads();
        sums[t] += v;
        __syncthreads();
    }
    int pre = (t == 0) ? 0 : sums[t - 1];
    for (int i = lo; i < hi; ++i) { rowptr[i] = pre; pre += deg[i] - 1; }
    if (t == 255) rowptr[n] = pre;
}

__global__ void fill_kernel(const int* __restrict__ src, const int* __restrict__ dst,
                            const int* __restrict__ rowptr, int* __restrict__ cursor,
                            int* __restrict__ csr, int e) {
    int i = blockIdx.x * blockDim.x + threadIdx.x;
    if (i < e) {
        int d = dst[i];
        int p = atomicAdd(&cursor[d], 1);
        csr[rowptr[d] + p] = src[i];
    }
}

// ---------------- conversions ----------------

__global__ void cvt_kernel(const float* __restrict__ in, u16* __restrict__ out, int n4) {
    int i = blockIdx.x * blockDim.x + threadIdx.x;
    if (i < n4) {
        float4 v = *reinterpret_cast<const float4*>(&in[(size_t)i * 4]);
        ushort4 o;
        o.x = f2bf(v.x); o.y = f2bf(v.y); o.z = f2bf(v.z); o.w = f2bf(v.w);
        *reinterpret_cast<ushort4*>(&out[(size_t)i * 4]) = o;
    }
}

// W [K=256][N=256] f32 -> Wt [N][K] bf16 (transpose + convert)
__global__ __launch_bounds__(256) void transpose_cvt_kernel(
    const float* __restrict__ W, u16* __restrict__ Wt) {
    __shared__ float t[32][33];
    int bx = blockIdx.x * 32, by = blockIdx.y * 32;
    int tx = threadIdx.x & 31, ty = threadIdx.x >> 5;
#pragma unroll
    for (int i = 0; i < 32; i += 8)
        t[ty + i][tx] = W[(size_t)(bx + ty + i) * D + by + tx];
    __syncthreads();
#pragma unroll
    for (int i = 0; i < 32; i += 8)
        Wt[(size_t)(by + ty + i) * D + bx + tx] = f2bf(t[tx][ty + i]);
}

// ---------------- bf16 MFMA GEMM ----------------
// A: [M][256] bf16 row-major; Bt: [256][256] bf16, Bt[n][k]
// mode 0: C = relu(A@B + bias[col]) -> bf16
// mode 1: C = (A@B) * dinv[row]     -> bf16
__global__ __launch_bounds__(256) void mfma_gemm(
    const u16* __restrict__ A, const u16* __restrict__ Bt,
    const float* __restrict__ bias, const float* __restrict__ dinv,
    u16* __restrict__ C, int M, int mode)
{
    __shared__ u16 As[128 * 32];
    __shared__ u16 Bs[128 * 32];
    const int tid = threadIdx.x;
    const int lane = tid & 63;
    const int wave = tid >> 6;
    const int wr = wave >> 1, wc = wave & 1;
    const int row0 = blockIdx.y * 128, col0 = blockIdx.x * 128;
    const int l16 = lane & 15, kg = lane >> 4;

    f32x4 acc[4][4] = {};

    for (int k0 = 0; k0 < D; k0 += 32) {
#pragma unroll
        for (int i = 0; i < 2; ++i) {
            int idx = i * 256 + tid;
            int r = idx >> 2, c = idx & 3;
            int csw = c ^ ((r >> 1) & 3);
            char* ldsbase_a = (char*)As + ((i * 256 + (tid & ~63)) << 4);
            char* ldsbase_b = (char*)Bs + ((i * 256 + (tid & ~63)) << 4);
            int grow = row0 + r; if (grow >= M) grow = M - 1;
            gload16(&A[(size_t)grow * D + k0 + csw * 8], ldsbase_a);
            gload16(&Bt[(size_t)(col0 + r) * D + k0 + csw * 8], ldsbase_b);
        }
        __syncthreads();
        bf16x8 af[4], bfr[4];
        int ksw = kg ^ ((l16 >> 1) & 3);
#pragma unroll
        for (int m = 0; m < 4; ++m) {
            int row = wr * 64 + m * 16 + l16;
            af[m] = *reinterpret_cast<const bf16x8*>(&As[row * 32 + ksw * 8]);
        }
#pragma unroll
        for (int nn = 0; nn < 4; ++nn) {
            int row = wc * 64 + nn * 16 + l16;
            bfr[nn] = *reinterpret_cast<const bf16x8*>(&Bs[row * 32 + ksw * 8]);
        }
#pragma unroll
        for (int m = 0; m < 4; ++m)
#pragma unroll
            for (int nn = 0; nn < 4; ++nn)
                acc[m][nn] = __builtin_amdgcn_mfma_f32_16x16x32_bf16(
                    af[m], bfr[nn], acc[m][nn], 0, 0, 0);
        __syncthreads();
    }

#pragma unroll
    for (int m = 0; m < 4; ++m) {
#pragma unroll
        for (int nn = 0; nn < 4; ++nn) {
            int gcol = col0 + wc * 64 + nn * 16 + l16;
#pragma unroll
            for (int j = 0; j < 4; ++j) {
                int grow = row0 + wr * 64 + m * 16 + kg * 4 + j;
                if (grow >= M) continue;
                float v = acc[m][nn][j];
                if (mode == 0) v = fmaxf(v + bias[gcol], 0.f);
                else           v *= dinv[grow];
                C[(size_t)grow * D + gcol] = f2bf(v);
            }
        }
    }
}

// ---------------- aggregation v2 ----------------
// out[d] = relu(dinv[d] * (hn[d] + sum_{s in in(d)} hn[s]) + bias[col])
// one wave per node; half-wave per edge (lane loads bf16x8 = 16B = 8 cols),
// 2 edges per iteration, unrolled x4 (8 edges / 4 loads in flight),
// csr indices prefetched 64 at a time and broadcast via shuffle.
__global__ __launch_bounds__(256) void agg_kernel(
    const u16* __restrict__ hn, const int* __restrict__ rowptr,
    const int* __restrict__ csr, const float* __restrict__ dinv,
    const float* __restrict__ bias,
    u16* __restrict__ out_bf, float* __restrict__ out_f32, int n)
{
    int wave = threadIdx.x >> 6;
    int lane = threadIdx.x & 63;
    int node = blockIdx.x * 4 + wave;
    if (node >= n) return;
    int h = lane >> 5;          // half-wave id: edge parity
    int l5 = lane & 31;
    int c8 = l5 * 8;            // column base (8 bf16 = 16B per lane)

    float a[8] = {0.f, 0.f, 0.f, 0.f, 0.f, 0.f, 0.f, 0.f};

#define ACC8(vv) { \
    a[0] += bf2f((u16)(vv)[0]); a[1] += bf2f((u16)(vv)[1]); \
    a[2] += bf2f((u16)(vv)[2]); a[3] += bf2f((u16)(vv)[3]); \
    a[4] += bf2f((u16)(vv)[4]); a[5] += bf2f((u16)(vv)[5]); \
    a[6] += bf2f((u16)(vv)[6]); a[7] += bf2f((u16)(vv)[7]); }

    // self loop: half 0 only (would double-count after combine otherwise)
    if (h == 0) {
        bf16x8 v = *reinterpret_cast<const bf16x8*>(&hn[(size_t)node * D + c8]);
        ACC8(v);
    }

    int e0 = rowptr[node], e1 = rowptr[node + 1];
    for (int base = e0; base < e1; base += 64) {
        int bi = base + lane;
        int idx = (bi < e1) ? csr[bi] : 0;     // 64 indices prefetched
        int cnt = e1 - base; if (cnt > 64) cnt = 64;
        int it = 0;
        for (; it + 8 <= cnt; it += 8) {
            int s0 = __shfl(idx, it + 0 + h);
            int s1 = __shfl(idx, it + 2 + h);
            int s2 = __shfl(idx, it + 4 + h);
            int s3 = __shfl(idx, it + 6 + h);
            bf16x8 v0 = *reinterpret_cast<const bf16x8*>(&hn[(size_t)s0 * D + c8]);
            bf16x8 v1 = *reinterpret_cast<const bf16x8*>(&hn[(size_t)s1 * D + c8]);
            bf16x8 v2 = *reinterpret_cast<const bf16x8*>(&hn[(size_t)s2 * D + c8]);
            bf16x8 v3 = *reinterpret_cast<const bf16x8*>(&hn[(size_t)s3 * D + c8]);
            ACC8(v0); ACC8(v1); ACC8(v2); ACC8(v3);
        }
        for (; it + 2 <= cnt; it += 2) {
            int s0 = __shfl(idx, it + h);
            bf16x8 v0 = *reinterpret_cast<const bf16x8*>(&hn[(size_t)s0 * D + c8]);
            ACC8(v0);
        }
        if (it < cnt) {                         // odd tail: half 0 only
            int s0 = __shfl(idx, it);
            if (h == 0) {
                bf16x8 v0 = *reinterpret_cast<const bf16x8*>(&hn[(size_t)s0 * D + c8]);
                ACC8(v0);
            }
        }
    }
#undef ACC8

    // combine halves: lane l <-> lane l^32 hold same columns
#pragma unroll
    for (int j = 0; j < 8; ++j) a[j] += __shfl(a[j], lane ^ 32);

    if (h == 0) {
        float di = dinv[node];
#pragma unroll
        for (int j = 0; j < 8; ++j) a[j] = fmaxf(a[j] * di + bias[c8 + j], 0.f);
        if (out_bf) {
            bf16x8 o;
#pragma unroll
            for (int j = 0; j < 8; ++j) o[j] = (short)f2bf(a[j]);
            *reinterpret_cast<bf16x8*>(&out_bf[(size_t)node * D + c8]) = o;
        } else {
            float4 o0, o1;
            o0.x = a[0]; o0.y = a[1]; o0.z = a[2]; o0.w = a[3];
            o1.x = a[4]; o1.y = a[5]; o1.z = a[6]; o1.w = a[7];
            *reinterpret_cast<float4*>(&out_f32[(size_t)node * D + c8 + 0]) = o0;
            *reinterpret_cast<float4*>(&out_f32[(size_t)node * D + c8 + 4]) = o1;
        }
    }
}

// ---------------- launch ----------------

extern "C" void kernel_launch(void* const* d_in, const int* in_sizes, int n_in,
                              void* d_out, int out_size, void* d_ws, size_t ws_size,
                              hipStream_t stream) {
    const float* input  = (const float*)d_in[0];
    const int*   edge   = (const int*)d_in[1];
    const float* weight = (const float*)d_in[2];
    const float* bias   = (const float*)d_in[3];
    const float* conv_w = (const float*)d_in[4];
    const float* conv_b = (const float*)d_in[5];
    float* out = (float*)d_out;

    const int n = in_sizes[0] / D;     // 50000
    const int E = in_sizes[1] / 2;     // 800000
    const int* src = edge;
    const int* dst = edge + E;

    char* ws = (char*)d_ws;
    size_t off = 0;
    auto alloc = [&](size_t bytes) -> void* {
        void* p = ws + off;
        off = (off + bytes + 255) & ~(size_t)255;
        return p;
    };
    u16*   Ain    = (u16*)alloc((size_t)n * D * sizeof(u16));
    u16*   bufA   = (u16*)alloc((size_t)n * D * sizeof(u16));
    u16*   bufB   = (u16*)alloc((size_t)n * D * sizeof(u16));
    u16*   Wt     = (u16*)alloc((size_t)3 * D * D * sizeof(u16));
    int*   deg    = (int*)alloc((size_t)n * sizeof(int));
    int*   cursor = (int*)alloc((size_t)n * sizeof(int));
    float* dinv   = (float*)alloc((size_t)n * sizeof(float));
    int*   rowptr = (int*)alloc((size_t)(n + 1) * sizeof(int));
    int*   csr    = (int*)alloc((size_t)E * sizeof(int));

    int nb = (n + 255) / 256;
    int eb = (E + 255) / 256;
    int eb4 = (E / 4 + 255) / 256;
    init_kernel<<<nb, 256, 0, stream>>>(deg, cursor, n);
    hist_kernel<<<eb4, 256, 0, stream>>>(dst, deg, E);
    dinv_kernel<<<nb, 256, 0, stream>>>(deg, dinv, n);
    scan_kernel<<<1, 256, 0, stream>>>(deg, rowptr, n);
    fill_kernel<<<eb, 256, 0, stream>>>(src, dst, rowptr, cursor, csr, E);

    int n4 = n * D / 4;
    cvt_kernel<<<(n4 + 255) / 256, 256, 0, stream>>>(input, Ain, n4);
    dim3 tgrid(8, 8);
    transpose_cvt_kernel<<<tgrid, 256, 0, stream>>>(weight, Wt);
    transpose_cvt_kernel<<<tgrid, 256, 0, stream>>>(conv_w, Wt + D * D);
    transpose_cvt_kernel<<<tgrid, 256, 0, stream>>>(conv_w + D * D, Wt + 2 * D * D);

    dim3 ggrid(D / 128, (n + 127) / 128);
    mfma_gemm<<<ggrid, 256, 0, stream>>>(Ain, Wt, bias, dinv, bufA, n, 0);
    mfma_gemm<<<ggrid, 256, 0, stream>>>(bufA, Wt + D * D, nullptr, dinv, bufB, n, 1);
    agg_kernel<<<(n + 3) / 4, 256, 0, stream>>>(bufB, rowptr, csr, dinv, conv_b, bufA, nullptr, n);
    mfma_gemm<<<ggrid, 256, 0, stream>>>(bufA, Wt + 2 * D * D, nullptr, dinv, bufB, n, 1);
    agg_kernel<<<(n + 3) / 4, 256, 0, stream>>>(bufB, rowptr, csr, dinv, conv_b + D, nullptr, out, n);
}

// Round 4
// 343.739 us; speedup vs baseline: 2.0864x; 1.2339x over previous
//
#include <hip/hip_runtime.h>

#define D 256
typedef unsigned short u16;
typedef __attribute__((ext_vector_type(8))) short bf16x8;
typedef __attribute__((ext_vector_type(4))) float f32x4;

__device__ __forceinline__ float bf2f(u16 u) {
    union { unsigned int i; float f; } x; x.i = ((unsigned int)u) << 16; return x.f;
}
__device__ __forceinline__ u16 f2bf(float f) {
    union { float f; unsigned int i; } x; x.f = f;
    unsigned int r = x.i + 0x7fff + ((x.i >> 16) & 1);   // RNE
    return (u16)(r >> 16);
}
__device__ __forceinline__ void gload16(const void* g, void* l) {
    __builtin_amdgcn_global_load_lds(
        (const __attribute__((address_space(1))) void*)g,
        (__attribute__((address_space(3))) void*)l, 16, 0, 0);
}

// ---------------- setup kernels ----------------

__global__ void init_kernel(int* __restrict__ deg, int* __restrict__ cursor, int n) {
    int i = blockIdx.x * blockDim.x + threadIdx.x;
    if (i < n) { deg[i] = 1; cursor[i] = 0; }   // deg starts at 1 (self-loop)
}

__global__ void hist_kernel(const int* __restrict__ dst, int* __restrict__ deg, int e) {
    int i = blockIdx.x * blockDim.x + threadIdx.x;
    int b = i * 4;
    if (b + 3 < e) {
        int4 v = *reinterpret_cast<const int4*>(&dst[b]);
        atomicAdd(&deg[v.x], 1); atomicAdd(&deg[v.y], 1);
        atomicAdd(&deg[v.z], 1); atomicAdd(&deg[v.w], 1);
    } else {
        for (int j = b; j < e; ++j) atomicAdd(&deg[dst[j]], 1);
    }
}

__global__ void dinv_kernel(const int* __restrict__ deg, float* __restrict__ dinv, int n) {
    int i = blockIdx.x * blockDim.x + threadIdx.x;
    if (i < n) dinv[i] = rsqrtf((float)deg[i]);
}

// ---------------- 3-phase exclusive scan of (deg[i]-1) -> rowptr[0..n] ----------------
// 1024 elements per block, 4 per thread.

__global__ __launch_bounds__(256) void scan_phase1(
    const int* __restrict__ deg, int* __restrict__ bsum, int n) {
    __shared__ int red[256];
    int t = threadIdx.x;
    int i0 = blockIdx.x * 1024 + t * 4;
    int s = 0;
    if (i0 + 3 < n) {
        int4 v = *reinterpret_cast<const int4*>(&deg[i0]);
        s = v.x + v.y + v.z + v.w - 4;
    } else {
        for (int j = i0; j < n && j < i0 + 4; ++j) s += deg[j] - 1;
    }
    red[t] = s;
    __syncthreads();
    for (int off = 128; off > 0; off >>= 1) {
        if (t < off) red[t] += red[t + off];
        __syncthreads();
    }
    if (t == 0) bsum[blockIdx.x] = red[0];
}

// single small block: exclusive-scan bsum[0..nblk) -> boff, write rowptr[n]=total
__global__ __launch_bounds__(256) void scan_phase2(
    const int* __restrict__ bsum, int* __restrict__ boff,
    int* __restrict__ rowptr, int nblk, int n) {
    __shared__ int sums[256];
    int t = threadIdx.x;
    int v = (t < nblk) ? bsum[t] : 0;
    int orig = v;
    sums[t] = v;
    __syncthreads();
    for (int off = 1; off < 256; off <<= 1) {
        int u = (t >= off) ? sums[t - off] : 0;
        __syncthreads();
        sums[t] += u;
        __syncthreads();
    }
    if (t < nblk) boff[t] = sums[t] - orig;
    if (t == nblk - 1) rowptr[n] = sums[t];
}

__global__ __launch_bounds__(256) void scan_phase3(
    const int* __restrict__ deg, const int* __restrict__ boff,
    int* __restrict__ rowptr, int n) {
    __shared__ int sums[256];
    int t = threadIdx.x;
    int i0 = blockIdx.x * 1024 + t * 4;
    int d0 = 0, d1 = 0, d2 = 0, d3 = 0;
    if (i0 + 3 < n) {
        int4 v = *reinterpret_cast<const int4*>(&deg[i0]);
        d0 = v.x - 1; d1 = v.y - 1; d2 = v.z - 1; d3 = v.w - 1;
    } else {
        if (i0 + 0 < n) d0 = deg[i0 + 0] - 1;
        if (i0 + 1 < n) d1 = deg[i0 + 1] - 1;
        if (i0 + 2 < n) d2 = deg[i0 + 2] - 1;
        if (i0 + 3 < n) d3 = deg[i0 + 3] - 1;
    }
    int ts = d0 + d1 + d2 + d3;
    sums[t] = ts;
    __syncthreads();
    for (int off = 1; off < 256; off <<= 1) {
        int u = (t >= off) ? sums[t - off] : 0;
        __syncthreads();
        sums[t] += u;
        __syncthreads();
    }
    int pre = boff[blockIdx.x] + sums[t] - ts;   // exclusive prefix for this thread
    if (i0 + 0 < n) rowptr[i0 + 0] = pre; pre += d0;
    if (i0 + 1 < n) rowptr[i0 + 1] = pre; pre += d1;
    if (i0 + 2 < n) rowptr[i0 + 2] = pre; pre += d2;
    if (i0 + 3 < n) rowptr[i0 + 3] = pre;
}

__global__ void fill_kernel(const int* __restrict__ src, const int* __restrict__ dst,
                            const int* __restrict__ rowptr, int* __restrict__ cursor,
                            int* __restrict__ csr, int e) {
    int i = blockIdx.x * blockDim.x + threadIdx.x;
    if (i < e) {
        int d = dst[i];
        int p = atomicAdd(&cursor[d], 1);
        csr[rowptr[d] + p] = src[i];
    }
}

// ---------------- conversions ----------------

__global__ void cvt_kernel(const float* __restrict__ in, u16* __restrict__ out, int n4) {
    int i = blockIdx.x * blockDim.x + threadIdx.x;
    if (i < n4) {
        float4 v = *reinterpret_cast<const float4*>(&in[(size_t)i * 4]);
        ushort4 o;
        o.x = f2bf(v.x); o.y = f2bf(v.y); o.z = f2bf(v.z); o.w = f2bf(v.w);
        *reinterpret_cast<ushort4*>(&out[(size_t)i * 4]) = o;
    }
}

// W [K=256][N=256] f32 -> Wt [N][K] bf16 (transpose + convert)
__global__ __launch_bounds__(256) void transpose_cvt_kernel(
    const float* __restrict__ W, u16* __restrict__ Wt) {
    __shared__ float t[32][33];
    int bx = blockIdx.x * 32, by = blockIdx.y * 32;
    int tx = threadIdx.x & 31, ty = threadIdx.x >> 5;
#pragma unroll
    for (int i = 0; i < 32; i += 8)
        t[ty + i][tx] = W[(size_t)(bx + ty + i) * D + by + tx];
    __syncthreads();
#pragma unroll
    for (int i = 0; i < 32; i += 8)
        Wt[(size_t)(by + ty + i) * D + bx + tx] = f2bf(t[tx][ty + i]);
}

// ---------------- bf16 MFMA GEMM ----------------
// A: [M][256] bf16 row-major; Bt: [256][256] bf16, Bt[n][k]
// mode 0: C = relu(A@B + bias[col]) -> bf16
// mode 1: C = (A@B) * dinv[row]     -> bf16
__global__ __launch_bounds__(256) void mfma_gemm(
    const u16* __restrict__ A, const u16* __restrict__ Bt,
    const float* __restrict__ bias, const float* __restrict__ dinv,
    u16* __restrict__ C, int M, int mode)
{
    __shared__ u16 As[128 * 32];
    __shared__ u16 Bs[128 * 32];
    const int tid = threadIdx.x;
    const int lane = tid & 63;
    const int wave = tid >> 6;
    const int wr = wave >> 1, wc = wave & 1;
    const int row0 = blockIdx.y * 128, col0 = blockIdx.x * 128;
    const int l16 = lane & 15, kg = lane >> 4;

    f32x4 acc[4][4] = {};

    for (int k0 = 0; k0 < D; k0 += 32) {
#pragma unroll
        for (int i = 0; i < 2; ++i) {
            int idx = i * 256 + tid;
            int r = idx >> 2, c = idx & 3;
            int csw = c ^ ((r >> 1) & 3);
            char* ldsbase_a = (char*)As + ((i * 256 + (tid & ~63)) << 4);
            char* ldsbase_b = (char*)Bs + ((i * 256 + (tid & ~63)) << 4);
            int grow = row0 + r; if (grow >= M) grow = M - 1;
            gload16(&A[(size_t)grow * D + k0 + csw * 8], ldsbase_a);
            gload16(&Bt[(size_t)(col0 + r) * D + k0 + csw * 8], ldsbase_b);
        }
        __syncthreads();
        bf16x8 af[4], bfr[4];
        int ksw = kg ^ ((l16 >> 1) & 3);
#pragma unroll
        for (int m = 0; m < 4; ++m) {
            int row = wr * 64 + m * 16 + l16;
            af[m] = *reinterpret_cast<const bf16x8*>(&As[row * 32 + ksw * 8]);
        }
#pragma unroll
        for (int nn = 0; nn < 4; ++nn) {
            int row = wc * 64 + nn * 16 + l16;
            bfr[nn] = *reinterpret_cast<const bf16x8*>(&Bs[row * 32 + ksw * 8]);
        }
#pragma unroll
        for (int m = 0; m < 4; ++m)
#pragma unroll
            for (int nn = 0; nn < 4; ++nn)
                acc[m][nn] = __builtin_amdgcn_mfma_f32_16x16x32_bf16(
                    af[m], bfr[nn], acc[m][nn], 0, 0, 0);
        __syncthreads();
    }

#pragma unroll
    for (int m = 0; m < 4; ++m) {
#pragma unroll
        for (int nn = 0; nn < 4; ++nn) {
            int gcol = col0 + wc * 64 + nn * 16 + l16;
#pragma unroll
            for (int j = 0; j < 4; ++j) {
                int grow = row0 + wr * 64 + m * 16 + kg * 4 + j;
                if (grow >= M) continue;
                float v = acc[m][nn][j];
                if (mode == 0) v = fmaxf(v + bias[gcol], 0.f);
                else           v *= dinv[grow];
                C[(size_t)grow * D + gcol] = f2bf(v);
            }
        }
    }
}

// ---------------- aggregation v2 ----------------
// out[d] = relu(dinv[d] * (hn[d] + sum_{s in in(d)} hn[s]) + bias[col])
__global__ __launch_bounds__(256) void agg_kernel(
    const u16* __restrict__ hn, const int* __restrict__ rowptr,
    const int* __restrict__ csr, const float* __restrict__ dinv,
    const float* __restrict__ bias,
    u16* __restrict__ out_bf, float* __restrict__ out_f32, int n)
{
    int wave = threadIdx.x >> 6;
    int lane = threadIdx.x & 63;
    int node = blockIdx.x * 4 + wave;
    if (node >= n) return;
    int h = lane >> 5;          // half-wave id: edge parity
    int l5 = lane & 31;
    int c8 = l5 * 8;            // column base (8 bf16 = 16B per lane)

    float a[8] = {0.f, 0.f, 0.f, 0.f, 0.f, 0.f, 0.f, 0.f};

#define ACC8(vv) { \
    a[0] += bf2f((u16)(vv)[0]); a[1] += bf2f((u16)(vv)[1]); \
    a[2] += bf2f((u16)(vv)[2]); a[3] += bf2f((u16)(vv)[3]); \
    a[4] += bf2f((u16)(vv)[4]); a[5] += bf2f((u16)(vv)[5]); \
    a[6] += bf2f((u16)(vv)[6]); a[7] += bf2f((u16)(vv)[7]); }

    if (h == 0) {
        bf16x8 v = *reinterpret_cast<const bf16x8*>(&hn[(size_t)node * D + c8]);
        ACC8(v);
    }

    int e0 = rowptr[node], e1 = rowptr[node + 1];
    for (int base = e0; base < e1; base += 64) {
        int bi = base + lane;
        int idx = (bi < e1) ? csr[bi] : 0;
        int cnt = e1 - base; if (cnt > 64) cnt = 64;
        int it = 0;
        for (; it + 8 <= cnt; it += 8) {
            int s0 = __shfl(idx, it + 0 + h);
            int s1 = __shfl(idx, it + 2 + h);
            int s2 = __shfl(idx, it + 4 + h);
            int s3 = __shfl(idx, it + 6 + h);
            bf16x8 v0 = *reinterpret_cast<const bf16x8*>(&hn[(size_t)s0 * D + c8]);
            bf16x8 v1 = *reinterpret_cast<const bf16x8*>(&hn[(size_t)s1 * D + c8]);
            bf16x8 v2 = *reinterpret_cast<const bf16x8*>(&hn[(size_t)s2 * D + c8]);
            bf16x8 v3 = *reinterpret_cast<const bf16x8*>(&hn[(size_t)s3 * D + c8]);
            ACC8(v0); ACC8(v1); ACC8(v2); ACC8(v3);
        }
        for (; it + 2 <= cnt; it += 2) {
            int s0 = __shfl(idx, it + h);
            bf16x8 v0 = *reinterpret_cast<const bf16x8*>(&hn[(size_t)s0 * D + c8]);
            ACC8(v0);
        }
        if (it < cnt) {
            int s0 = __shfl(idx, it);
            if (h == 0) {
                bf16x8 v0 = *reinterpret_cast<const bf16x8*>(&hn[(size_t)s0 * D + c8]);
                ACC8(v0);
            }
        }
    }
#undef ACC8

#pragma unroll
    for (int j = 0; j < 8; ++j) a[j] += __shfl(a[j], lane ^ 32);

    if (h == 0) {
        float di = dinv[node];
#pragma unroll
        for (int j = 0; j < 8; ++j) a[j] = fmaxf(a[j] * di + bias[c8 + j], 0.f);
        if (out_bf) {
            bf16x8 o;
#pragma unroll
            for (int j = 0; j < 8; ++j) o[j] = (short)f2bf(a[j]);
            *reinterpret_cast<bf16x8*>(&out_bf[(size_t)node * D + c8]) = o;
        } else {
            float4 o0, o1;
            o0.x = a[0]; o0.y = a[1]; o0.z = a[2]; o0.w = a[3];
            o1.x = a[4]; o1.y = a[5]; o1.z = a[6]; o1.w = a[7];
            *reinterpret_cast<float4*>(&out_f32[(size_t)node * D + c8 + 0]) = o0;
            *reinterpret_cast<float4*>(&out_f32[(size_t)node * D + c8 + 4]) = o1;
        }
    }
}

// ---------------- launch ----------------

extern "C" void kernel_launch(void* const* d_in, const int* in_sizes, int n_in,
                              void* d_out, int out_size, void* d_ws, size_t ws_size,
                              hipStream_t stream) {
    const float* input  = (const float*)d_in[0];
    const int*   edge   = (const int*)d_in[1];
    const float* weight = (const float*)d_in[2];
    const float* bias   = (const float*)d_in[3];
    const float* conv_w = (const float*)d_in[4];
    const float* conv_b = (const float*)d_in[5];
    float* out = (float*)d_out;

    const int n = in_sizes[0] / D;     // 50000
    const int E = in_sizes[1] / 2;     // 800000
    const int* src = edge;
    const int* dst = edge + E;

    char* ws = (char*)d_ws;
    size_t off = 0;
    auto alloc = [&](size_t bytes) -> void* {
        void* p = ws + off;
        off = (off + bytes + 255) & ~(size_t)255;
        return p;
    };
    u16*   Ain    = (u16*)alloc((size_t)n * D * sizeof(u16));
    u16*   bufA   = (u16*)alloc((size_t)n * D * sizeof(u16));
    u16*   bufB   = (u16*)alloc((size_t)n * D * sizeof(u16));
    u16*   Wt     = (u16*)alloc((size_t)3 * D * D * sizeof(u16));
    int*   deg    = (int*)alloc((size_t)n * sizeof(int));
    int*   cursor = (int*)alloc((size_t)n * sizeof(int));
    float* dinv   = (float*)alloc((size_t)n * sizeof(float));
    int*   rowptr = (int*)alloc((size_t)(n + 1) * sizeof(int));
    int*   csr    = (int*)alloc((size_t)E * sizeof(int));
    int    nscan  = (n + 1023) / 1024;
    int*   bsum   = (int*)alloc((size_t)nscan * sizeof(int));
    int*   boff   = (int*)alloc((size_t)nscan * sizeof(int));

    int nb = (n + 255) / 256;
    int eb = (E + 255) / 256;
    int eb4 = (E / 4 + 255) / 256;
    init_kernel<<<nb, 256, 0, stream>>>(deg, cursor, n);
    hist_kernel<<<eb4, 256, 0, stream>>>(dst, deg, E);
    dinv_kernel<<<nb, 256, 0, stream>>>(deg, dinv, n);
    scan_phase1<<<nscan, 256, 0, stream>>>(deg, bsum, n);
    scan_phase2<<<1, 256, 0, stream>>>(bsum, boff, rowptr, nscan, n);
    scan_phase3<<<nscan, 256, 0, stream>>>(deg, boff, rowptr, n);
    fill_kernel<<<eb, 256, 0, stream>>>(src, dst, rowptr, cursor, csr, E);

    int n4 = n * D / 4;
    cvt_kernel<<<(n4 + 255) / 256, 256, 0, stream>>>(input, Ain, n4);
    dim3 tgrid(8, 8);
    transpose_cvt_kernel<<<tgrid, 256, 0, stream>>>(weight, Wt);
    transpose_cvt_kernel<<<tgrid, 256, 0, stream>>>(conv_w, Wt + D * D);
    transpose_cvt_kernel<<<tgrid, 256, 0, stream>>>(conv_w + D * D, Wt + 2 * D * D);

    dim3 ggrid(D / 128, (n + 127) / 128);
    mfma_gemm<<<ggrid, 256, 0, stream>>>(Ain, Wt, bias, dinv, bufA, n, 0);
    mfma_gemm<<<ggrid, 256, 0, stream>>>(bufA, Wt + D * D, nullptr, dinv, bufB, n, 1);
    agg_kernel<<<(n + 3) / 4, 256, 0, stream>>>(bufB, rowptr, csr, dinv, conv_b, bufA, nullptr, n);
    mfma_gemm<<<ggrid, 256, 0, stream>>>(bufA, Wt + 2 * D * D, nullptr, dinv, bufB, n, 1);
    agg_kernel<<<(n + 3) / 4, 256, 0, stream>>>(bufB, rowptr, csr, dinv, conv_b + D, nullptr, out, n);
}

// Round 5
// 329.922 us; speedup vs baseline: 2.1738x; 1.0419x over previous
//
#include <hip/hip_runtime.h>

#define D 256
typedef unsigned short u16;
typedef __attribute__((ext_vector_type(8))) short bf16x8;
typedef __attribute__((ext_vector_type(4))) float f32x4;

__device__ __forceinline__ float bf2f(u16 u) {
    union { unsigned int i; float f; } x; x.i = ((unsigned int)u) << 16; return x.f;
}
__device__ __forceinline__ u16 f2bf(float f) {
    union { float f; unsigned int i; } x; x.f = f;
    unsigned int r = x.i + 0x7fff + ((x.i >> 16) & 1);   // RNE
    return (u16)(r >> 16);
}
__device__ __forceinline__ unsigned int cvtpk_bf16(float lo, float hi) {
    unsigned int r;
    asm("v_cvt_pk_bf16_f32 %0, %1, %2" : "=v"(r) : "v"(lo), "v"(hi));
    return r;
}
__device__ __forceinline__ void gload16(const void* g, void* l) {
    __builtin_amdgcn_global_load_lds(
        (const __attribute__((address_space(1))) void*)g,
        (__attribute__((address_space(3))) void*)l, 16, 0, 0);
}

// ---------------- setup kernels ----------------

__global__ void init_kernel(int* __restrict__ deg, int* __restrict__ cursor, int n) {
    int i = blockIdx.x * blockDim.x + threadIdx.x;
    if (i < n) { deg[i] = 1; cursor[i] = 0; }   // deg starts at 1 (self-loop)
}

__global__ void hist_kernel(const int* __restrict__ dst, int* __restrict__ deg, int e) {
    int i = blockIdx.x * blockDim.x + threadIdx.x;
    int b = i * 4;
    if (b + 3 < e) {
        int4 v = *reinterpret_cast<const int4*>(&dst[b]);
        atomicAdd(&deg[v.x], 1); atomicAdd(&deg[v.y], 1);
        atomicAdd(&deg[v.z], 1); atomicAdd(&deg[v.w], 1);
    } else {
        for (int j = b; j < e; ++j) atomicAdd(&deg[dst[j]], 1);
    }
}

// ---------------- 3-phase exclusive scan of (deg[i]-1) -> rowptr[0..n] ----------------
// phase1 also produces dinv (reads deg anyway). 1024 elements per block.

__global__ __launch_bounds__(256) void scan_phase1(
    const int* __restrict__ deg, int* __restrict__ bsum,
    float* __restrict__ dinv, int n) {
    __shared__ int red[256];
    int t = threadIdx.x;
    int i0 = blockIdx.x * 1024 + t * 4;
    int s = 0;
    if (i0 + 3 < n) {
        int4 v = *reinterpret_cast<const int4*>(&deg[i0]);
        s = v.x + v.y + v.z + v.w - 4;
        float4 dv;
        dv.x = rsqrtf((float)v.x); dv.y = rsqrtf((float)v.y);
        dv.z = rsqrtf((float)v.z); dv.w = rsqrtf((float)v.w);
        *reinterpret_cast<float4*>(&dinv[i0]) = dv;
    } else {
        for (int j = i0; j < n && j < i0 + 4; ++j) {
            s += deg[j] - 1;
            dinv[j] = rsqrtf((float)deg[j]);
        }
    }
    red[t] = s;
    __syncthreads();
    for (int off = 128; off > 0; off >>= 1) {
        if (t < off) red[t] += red[t + off];
        __syncthreads();
    }
    if (t == 0) bsum[blockIdx.x] = red[0];
}

__global__ __launch_bounds__(256) void scan_phase2(
    const int* __restrict__ bsum, int* __restrict__ boff,
    int* __restrict__ rowptr, int nblk, int n) {
    __shared__ int sums[256];
    int t = threadIdx.x;
    int v = (t < nblk) ? bsum[t] : 0;
    int orig = v;
    sums[t] = v;
    __syncthreads();
    for (int off = 1; off < 256; off <<= 1) {
        int u = (t >= off) ? sums[t - off] : 0;
        __syncthreads();
        sums[t] += u;
        __syncthreads();
    }
    if (t < nblk) boff[t] = sums[t] - orig;
    if (t == nblk - 1) rowptr[n] = sums[t];
}

__global__ __launch_bounds__(256) void scan_phase3(
    const int* __restrict__ deg, const int* __restrict__ boff,
    int* __restrict__ rowptr, int n) {
    __shared__ int sums[256];
    int t = threadIdx.x;
    int i0 = blockIdx.x * 1024 + t * 4;
    int d0 = 0, d1 = 0, d2 = 0, d3 = 0;
    if (i0 + 3 < n) {
        int4 v = *reinterpret_cast<const int4*>(&deg[i0]);
        d0 = v.x - 1; d1 = v.y - 1; d2 = v.z - 1; d3 = v.w - 1;
    } else {
        if (i0 + 0 < n) d0 = deg[i0 + 0] - 1;
        if (i0 + 1 < n) d1 = deg[i0 + 1] - 1;
        if (i0 + 2 < n) d2 = deg[i0 + 2] - 1;
        if (i0 + 3 < n) d3 = deg[i0 + 3] - 1;
    }
    int ts = d0 + d1 + d2 + d3;
    sums[t] = ts;
    __syncthreads();
    for (int off = 1; off < 256; off <<= 1) {
        int u = (t >= off) ? sums[t - off] : 0;
        __syncthreads();
        sums[t] += u;
        __syncthreads();
    }
    int pre = boff[blockIdx.x] + sums[t] - ts;
    if (i0 + 0 < n) rowptr[i0 + 0] = pre; pre += d0;
    if (i0 + 1 < n) rowptr[i0 + 1] = pre; pre += d1;
    if (i0 + 2 < n) rowptr[i0 + 2] = pre; pre += d2;
    if (i0 + 3 < n) rowptr[i0 + 3] = pre;
}

__global__ void fill_kernel(const int* __restrict__ src, const int* __restrict__ dst,
                            const int* __restrict__ rowptr, int* __restrict__ cursor,
                            int* __restrict__ csr, int e) {
    int i = blockIdx.x * blockDim.x + threadIdx.x;
    int b = i * 4;
    if (b + 3 < e) {
        int4 s4 = *reinterpret_cast<const int4*>(&src[b]);
        int4 d4 = *reinterpret_cast<const int4*>(&dst[b]);
        int p;
        p = atomicAdd(&cursor[d4.x], 1); csr[rowptr[d4.x] + p] = s4.x;
        p = atomicAdd(&cursor[d4.y], 1); csr[rowptr[d4.y] + p] = s4.y;
        p = atomicAdd(&cursor[d4.z], 1); csr[rowptr[d4.z] + p] = s4.z;
        p = atomicAdd(&cursor[d4.w], 1); csr[rowptr[d4.w] + p] = s4.w;
    } else {
        for (int j = b; j < e; ++j) {
            int d = dst[j];
            int p = atomicAdd(&cursor[d], 1);
            csr[rowptr[d] + p] = src[j];
        }
    }
}

// ---------------- conversions ----------------

// W [K=256][N=256] f32 -> Wt [N][K] bf16 (transpose + convert)
__global__ __launch_bounds__(256) void transpose_cvt_kernel(
    const float* __restrict__ W, u16* __restrict__ Wt) {
    __shared__ float t[32][33];
    int bx = blockIdx.x * 32, by = blockIdx.y * 32;
    int tx = threadIdx.x & 31, ty = threadIdx.x >> 5;
#pragma unroll
    for (int i = 0; i < 32; i += 8)
        t[ty + i][tx] = W[(size_t)(bx + ty + i) * D + by + tx];
    __syncthreads();
#pragma unroll
    for (int i = 0; i < 32; i += 8)
        Wt[(size_t)(by + ty + i) * D + bx + tx] = f2bf(t[tx][ty + i]);
}

// ---------------- bf16 MFMA GEMM (shared MFMA/read-path structure) ----------------
// Bt: [256][256] bf16, Bt[n][k]. tile 128x128, BK=32, 4 waves (2x2).
// LDS layout (both variants): slot idx=(r*4+c), 16B each; content = global
// k-chunk (c ^ ((r>>1)&3)) of row r. Read with ksw = kg ^ ((l16>>1)&3).

// Variant A: A is bf16 (gload16 direct-to-LDS). mode 1 epilogue: *dinv[row].
__global__ __launch_bounds__(256) void mfma_gemm(
    const u16* __restrict__ A, const u16* __restrict__ Bt,
    const float* __restrict__ dinv,
    u16* __restrict__ C, int M)
{
    __shared__ u16 As[128 * 32];
    __shared__ u16 Bs[128 * 32];
    const int tid = threadIdx.x;
    const int lane = tid & 63;
    const int wave = tid >> 6;
    const int wr = wave >> 1, wc = wave & 1;
    const int row0 = blockIdx.y * 128, col0 = blockIdx.x * 128;
    const int l16 = lane & 15, kg = lane >> 4;

    f32x4 acc[4][4] = {};

    for (int k0 = 0; k0 < D; k0 += 32) {
#pragma unroll
        for (int i = 0; i < 2; ++i) {
            int idx = i * 256 + tid;
            int r = idx >> 2, c = idx & 3;
            int csw = c ^ ((r >> 1) & 3);
            char* ldsbase_a = (char*)As + ((i * 256 + (tid & ~63)) << 4);
            char* ldsbase_b = (char*)Bs + ((i * 256 + (tid & ~63)) << 4);
            int grow = row0 + r; if (grow >= M) grow = M - 1;
            gload16(&A[(size_t)grow * D + k0 + csw * 8], ldsbase_a);
            gload16(&Bt[(size_t)(col0 + r) * D + k0 + csw * 8], ldsbase_b);
        }
        __syncthreads();
        bf16x8 af[4], bfr[4];
        int ksw = kg ^ ((l16 >> 1) & 3);
#pragma unroll
        for (int m = 0; m < 4; ++m)
            af[m] = *reinterpret_cast<const bf16x8*>(&As[(wr * 64 + m * 16 + l16) * 32 + ksw * 8]);
#pragma unroll
        for (int nn = 0; nn < 4; ++nn)
            bfr[nn] = *reinterpret_cast<const bf16x8*>(&Bs[(wc * 64 + nn * 16 + l16) * 32 + ksw * 8]);
#pragma unroll
        for (int m = 0; m < 4; ++m)
#pragma unroll
            for (int nn = 0; nn < 4; ++nn)
                acc[m][nn] = __builtin_amdgcn_mfma_f32_16x16x32_bf16(
                    af[m], bfr[nn], acc[m][nn], 0, 0, 0);
        __syncthreads();
    }

#pragma unroll
    for (int m = 0; m < 4; ++m) {
#pragma unroll
        for (int nn = 0; nn < 4; ++nn) {
            int gcol = col0 + wc * 64 + nn * 16 + l16;
#pragma unroll
            for (int j = 0; j < 4; ++j) {
                int grow = row0 + wr * 64 + m * 16 + kg * 4 + j;
                if (grow >= M) continue;
                C[(size_t)grow * D + gcol] = f2bf(acc[m][nn][j] * dinv[grow]);
            }
        }
    }
}

// Variant B: A is f32 (reg-stage + cvt_pk + ds_write, fuses the cvt pass).
// mode 0 epilogue: relu(+bias[col]).
__global__ __launch_bounds__(256) void mfma_gemm_f32a(
    const float* __restrict__ A, const u16* __restrict__ Bt,
    const float* __restrict__ bias,
    u16* __restrict__ C, int M)
{
    __shared__ u16 As[128 * 32];
    __shared__ u16 Bs[128 * 32];
    const int tid = threadIdx.x;
    const int lane = tid & 63;
    const int wave = tid >> 6;
    const int wr = wave >> 1, wc = wave & 1;
    const int row0 = blockIdx.y * 128, col0 = blockIdx.x * 128;
    const int l16 = lane & 15, kg = lane >> 4;

    f32x4 acc[4][4] = {};

    for (int k0 = 0; k0 < D; k0 += 32) {
        // B: gload16 direct (unchanged layout)
#pragma unroll
        for (int i = 0; i < 2; ++i) {
            int idx = i * 256 + tid;
            int r = idx >> 2, c = idx & 3;
            int csw = c ^ ((r >> 1) & 3);
            char* ldsbase_b = (char*)Bs + ((i * 256 + (tid & ~63)) << 4);
            gload16(&Bt[(size_t)(col0 + r) * D + k0 + csw * 8], ldsbase_b);
        }
        // A: f32 load x2 -> cvt_pk -> ds_write_b128, same swizzled slots
#pragma unroll
        for (int i = 0; i < 4; ++i) {
            int idx = i * 256 + tid;          // 0..1023
            int r = idx >> 3, c = idx & 7;    // wait: 1024 slots? no -- see below
            // 128 rows x 4 chunks = 512 slots of 16B; each thread does 2 slots
        }
        // redo properly: 512 slots, 2 per thread
#pragma unroll
        for (int i = 0; i < 2; ++i) {
            int idx = i * 256 + tid;          // slot id 0..511
            int r = idx >> 2, c = idx & 3;
            int csw = c ^ ((r >> 1) & 3);
            int grow = row0 + r; if (grow >= M) grow = M - 1;
            const float* gp = &A[(size_t)grow * D + k0 + csw * 8];
            float4 v0 = *reinterpret_cast<const float4*>(gp);
            float4 v1 = *reinterpret_cast<const float4*>(gp + 4);
            uint4 w;
            w.x = cvtpk_bf16(v0.x, v0.y);
            w.y = cvtpk_bf16(v0.z, v0.w);
            w.z = cvtpk_bf16(v1.x, v1.y);
            w.w = cvtpk_bf16(v1.z, v1.w);
            *reinterpret_cast<uint4*>((char*)As + (idx << 4)) = w;
        }
        __syncthreads();
        bf16x8 af[4], bfr[4];
        int ksw = kg ^ ((l16 >> 1) & 3);
#pragma unroll
        for (int m = 0; m < 4; ++m)
            af[m] = *reinterpret_cast<const bf16x8*>(&As[(wr * 64 + m * 16 + l16) * 32 + ksw * 8]);
#pragma unroll
        for (int nn = 0; nn < 4; ++nn)
            bfr[nn] = *reinterpret_cast<const bf16x8*>(&Bs[(wc * 64 + nn * 16 + l16) * 32 + ksw * 8]);
#pragma unroll
        for (int m = 0; m < 4; ++m)
#pragma unroll
            for (int nn = 0; nn < 4; ++nn)
                acc[m][nn] = __builtin_amdgcn_mfma_f32_16x16x32_bf16(
                    af[m], bfr[nn], acc[m][nn], 0, 0, 0);
        __syncthreads();
    }

#pragma unroll
    for (int m = 0; m < 4; ++m) {
#pragma unroll
        for (int nn = 0; nn < 4; ++nn) {
            int gcol = col0 + wc * 64 + nn * 16 + l16;
#pragma unroll
            for (int j = 0; j < 4; ++j) {
                int grow = row0 + wr * 64 + m * 16 + kg * 4 + j;
                if (grow >= M) continue;
                C[(size_t)grow * D + gcol] = f2bf(fmaxf(acc[m][nn][j] + bias[gcol], 0.f));
            }
        }
    }
}

// ---------------- aggregation v3 (16-edge unroll, 8 loads in flight) ----------------
// out[d] = relu(dinv[d] * (hn[d] + sum_{s in in(d)} hn[s]) + bias[col])
__global__ __launch_bounds__(256) void agg_kernel(
    const u16* __restrict__ hn, const int* __restrict__ rowptr,
    const int* __restrict__ csr, const float* __restrict__ dinv,
    const float* __restrict__ bias,
    u16* __restrict__ out_bf, float* __restrict__ out_f32, int n)
{
    int wave = threadIdx.x >> 6;
    int lane = threadIdx.x & 63;
    int node = blockIdx.x * 4 + wave;
    if (node >= n) return;
    int h = lane >> 5;          // half-wave id: edge parity
    int l5 = lane & 31;
    int c8 = l5 * 8;            // column base (8 bf16 = 16B per lane)

    float a[8] = {0.f, 0.f, 0.f, 0.f, 0.f, 0.f, 0.f, 0.f};

#define ACC8(vv) { \
    a[0] += bf2f((u16)(vv)[0]); a[1] += bf2f((u16)(vv)[1]); \
    a[2] += bf2f((u16)(vv)[2]); a[3] += bf2f((u16)(vv)[3]); \
    a[4] += bf2f((u16)(vv)[4]); a[5] += bf2f((u16)(vv)[5]); \
    a[6] += bf2f((u16)(vv)[6]); a[7] += bf2f((u16)(vv)[7]); }
#define LOADROW(s) (*reinterpret_cast<const bf16x8*>(&hn[(size_t)(s) * D + c8]))

    if (h == 0) { bf16x8 v = LOADROW(node); ACC8(v); }

    int e0 = rowptr[node], e1 = rowptr[node + 1];
    for (int base = e0; base < e1; base += 64) {
        int bi = base + lane;
        int idx = (bi < e1) ? csr[bi] : 0;
        int cnt = e1 - base; if (cnt > 64) cnt = 64;
        int it = 0;
        for (; it + 16 <= cnt; it += 16) {
            int s0 = __shfl(idx, it + 0  + h);
            int s1 = __shfl(idx, it + 2  + h);
            int s2 = __shfl(idx, it + 4  + h);
            int s3 = __shfl(idx, it + 6  + h);
            int s4 = __shfl(idx, it + 8  + h);
            int s5 = __shfl(idx, it + 10 + h);
            int s6 = __shfl(idx, it + 12 + h);
            int s7 = __shfl(idx, it + 14 + h);
            bf16x8 v0 = LOADROW(s0); bf16x8 v1 = LOADROW(s1);
            bf16x8 v2 = LOADROW(s2); bf16x8 v3 = LOADROW(s3);
            bf16x8 v4 = LOADROW(s4); bf16x8 v5 = LOADROW(s5);
            bf16x8 v6 = LOADROW(s6); bf16x8 v7 = LOADROW(s7);
            ACC8(v0); ACC8(v1); ACC8(v2); ACC8(v3);
            ACC8(v4); ACC8(v5); ACC8(v6); ACC8(v7);
        }
        for (; it + 8 <= cnt; it += 8) {
            int s0 = __shfl(idx, it + 0 + h);
            int s1 = __shfl(idx, it + 2 + h);
            int s2 = __shfl(idx, it + 4 + h);
            int s3 = __shfl(idx, it + 6 + h);
            bf16x8 v0 = LOADROW(s0); bf16x8 v1 = LOADROW(s1);
            bf16x8 v2 = LOADROW(s2); bf16x8 v3 = LOADROW(s3);
            ACC8(v0); ACC8(v1); ACC8(v2); ACC8(v3);
        }
        for (; it + 2 <= cnt; it += 2) {
            int s0 = __shfl(idx, it + h);
            bf16x8 v0 = LOADROW(s0);
            ACC8(v0);
        }
        if (it < cnt) {
            int s0 = __shfl(idx, it);
            if (h == 0) { bf16x8 v0 = LOADROW(s0); ACC8(v0); }
        }
    }
#undef ACC8
#undef LOADROW

#pragma unroll
    for (int j = 0; j < 8; ++j) a[j] += __shfl(a[j], lane ^ 32);

    if (h == 0) {
        float di = dinv[node];
#pragma unroll
        for (int j = 0; j < 8; ++j) a[j] = fmaxf(a[j] * di + bias[c8 + j], 0.f);
        if (out_bf) {
            bf16x8 o;
#pragma unroll
            for (int j = 0; j < 8; ++j) o[j] = (short)f2bf(a[j]);
            *reinterpret_cast<bf16x8*>(&out_bf[(size_t)node * D + c8]) = o;
        } else {
            float4 o0, o1;
            o0.x = a[0]; o0.y = a[1]; o0.z = a[2]; o0.w = a[3];
            o1.x = a[4]; o1.y = a[5]; o1.z = a[6]; o1.w = a[7];
            *reinterpret_cast<float4*>(&out_f32[(size_t)node * D + c8 + 0]) = o0;
            *reinterpret_cast<float4*>(&out_f32[(size_t)node * D + c8 + 4]) = o1;
        }
    }
}

// ---------------- launch ----------------

extern "C" void kernel_launch(void* const* d_in, const int* in_sizes, int n_in,
                              void* d_out, int out_size, void* d_ws, size_t ws_size,
                              hipStream_t stream) {
    const float* input  = (const float*)d_in[0];
    const int*   edge   = (const int*)d_in[1];
    const float* weight = (const float*)d_in[2];
    const float* bias   = (const float*)d_in[3];
    const float* conv_w = (const float*)d_in[4];
    const float* conv_b = (const float*)d_in[5];
    float* out = (float*)d_out;

    const int n = in_sizes[0] / D;     // 50000
    const int E = in_sizes[1] / 2;     // 800000
    const int* src = edge;
    const int* dst = edge + E;

    char* ws = (char*)d_ws;
    size_t off = 0;
    auto alloc = [&](size_t bytes) -> void* {
        void* p = ws + off;
        off = (off + bytes + 255) & ~(size_t)255;
        return p;
    };
    u16*   bufA   = (u16*)alloc((size_t)n * D * sizeof(u16));
    u16*   bufB   = (u16*)alloc((size_t)n * D * sizeof(u16));
    u16*   Wt     = (u16*)alloc((size_t)3 * D * D * sizeof(u16));
    int*   deg    = (int*)alloc((size_t)n * sizeof(int));
    int*   cursor = (int*)alloc((size_t)n * sizeof(int));
    float* dinv   = (float*)alloc((size_t)n * sizeof(float));
    int*   rowptr = (int*)alloc((size_t)(n + 1) * sizeof(int));
    int*   csr    = (int*)alloc((size_t)E * sizeof(int));
    int    nscan  = (n + 1023) / 1024;
    int*   bsum   = (int*)alloc((size_t)nscan * sizeof(int));
    int*   boff   = (int*)alloc((size_t)nscan * sizeof(int));

    int nb = (n + 255) / 256;
    int eb4 = (E / 4 + 255) / 256;
    init_kernel<<<nb, 256, 0, stream>>>(deg, cursor, n);
    hist_kernel<<<eb4, 256, 0, stream>>>(dst, deg, E);
    scan_phase1<<<nscan, 256, 0, stream>>>(deg, bsum, dinv, n);
    scan_phase2<<<1, 256, 0, stream>>>(bsum, boff, rowptr, nscan, n);
    scan_phase3<<<nscan, 256, 0, stream>>>(deg, boff, rowptr, n);
    fill_kernel<<<eb4, 256, 0, stream>>>(src, dst, rowptr, cursor, csr, E);

    dim3 tgrid(8, 8);
    transpose_cvt_kernel<<<tgrid, 256, 0, stream>>>(weight, Wt);
    transpose_cvt_kernel<<<tgrid, 256, 0, stream>>>(conv_w, Wt + D * D);
    transpose_cvt_kernel<<<tgrid, 256, 0, stream>>>(conv_w + D * D, Wt + 2 * D * D);

    dim3 ggrid(D / 128, (n + 127) / 128);
    // x1 = relu(input @ W + b)        -> bufA (bf16), fuses f32->bf16 cvt of input
    mfma_gemm_f32a<<<ggrid, 256, 0, stream>>>(input, Wt, bias, bufA, n);
    // hn = (x1 @ W0) * dinv[row]      -> bufB
    mfma_gemm<<<ggrid, 256, 0, stream>>>(bufA, Wt + D * D, dinv, bufB, n);
    // x2 = relu(dinv * agg(hn) + b0)  -> bufA
    agg_kernel<<<(n + 3) / 4, 256, 0, stream>>>(bufB, rowptr, csr, dinv, conv_b, bufA, nullptr, n);
    // hn2 = (x2 @ W1) * dinv[row]     -> bufB
    mfma_gemm<<<ggrid, 256, 0, stream>>>(bufA, Wt + 2 * D * D, dinv, bufB, n);
    // out = relu(dinv * agg(hn2) + b1) -> out (f32)
    agg_kernel<<<(n + 3) / 4, 256, 0, stream>>>(bufB, rowptr, csr, dinv, conv_b + D, nullptr, out, n);
}

// Round 6
// 329.160 us; speedup vs baseline: 2.1788x; 1.0023x over previous
//
#include <hip/hip_runtime.h>

#define D 256
typedef unsigned short u16;
typedef __attribute__((ext_vector_type(8))) short bf16x8;
typedef __attribute__((ext_vector_type(4))) float f32x4;

__device__ __forceinline__ float bf2f(u16 u) {
    union { unsigned int i; float f; } x; x.i = ((unsigned int)u) << 16; return x.f;
}
__device__ __forceinline__ u16 f2bf(float f) {
    union { float f; unsigned int i; } x; x.f = f;
    unsigned int r = x.i + 0x7fff + ((x.i >> 16) & 1);   // RNE
    return (u16)(r >> 16);
}
__device__ __forceinline__ unsigned int cvtpk_bf16(float lo, float hi) {
    unsigned int r;
    asm("v_cvt_pk_bf16_f32 %0, %1, %2" : "=v"(r) : "v"(lo), "v"(hi));
    return r;
}
__device__ __forceinline__ void gload16(const void* g, void* l) {
    __builtin_amdgcn_global_load_lds(
        (const __attribute__((address_space(1))) void*)g,
        (__attribute__((address_space(3))) void*)l, 16, 0, 0);
}
// opaque 16B load the compiler cannot serialize (forced MLP)
__device__ __forceinline__ bf16x8 gload_row(const u16* p) {
    bf16x8 r;
    asm volatile("global_load_dwordx4 %0, %1, off" : "=&v"(r) : "v"(p));
    return r;
}

// ---------------- setup kernels ----------------

__global__ void init_kernel(int* __restrict__ deg, int* __restrict__ cursor, int n) {
    int i = blockIdx.x * blockDim.x + threadIdx.x;
    if (i < n) { deg[i] = 1; cursor[i] = 0; }   // deg starts at 1 (self-loop)
}

__global__ void hist_kernel(const int* __restrict__ dst, int* __restrict__ deg, int e) {
    int i = blockIdx.x * blockDim.x + threadIdx.x;
    int b = i * 4;
    if (b + 3 < e) {
        int4 v = *reinterpret_cast<const int4*>(&dst[b]);
        atomicAdd(&deg[v.x], 1); atomicAdd(&deg[v.y], 1);
        atomicAdd(&deg[v.z], 1); atomicAdd(&deg[v.w], 1);
    } else {
        for (int j = b; j < e; ++j) atomicAdd(&deg[dst[j]], 1);
    }
}

// ---------------- 3-phase exclusive scan of (deg[i]-1) -> rowptr[0..n] ----------------

__global__ __launch_bounds__(256) void scan_phase1(
    const int* __restrict__ deg, int* __restrict__ bsum,
    float* __restrict__ dinv, int n) {
    __shared__ int red[256];
    int t = threadIdx.x;
    int i0 = blockIdx.x * 1024 + t * 4;
    int s = 0;
    if (i0 + 3 < n) {
        int4 v = *reinterpret_cast<const int4*>(&deg[i0]);
        s = v.x + v.y + v.z + v.w - 4;
        float4 dv;
        dv.x = rsqrtf((float)v.x); dv.y = rsqrtf((float)v.y);
        dv.z = rsqrtf((float)v.z); dv.w = rsqrtf((float)v.w);
        *reinterpret_cast<float4*>(&dinv[i0]) = dv;
    } else {
        for (int j = i0; j < n && j < i0 + 4; ++j) {
            s += deg[j] - 1;
            dinv[j] = rsqrtf((float)deg[j]);
        }
    }
    red[t] = s;
    __syncthreads();
    for (int off = 128; off > 0; off >>= 1) {
        if (t < off) red[t] += red[t + off];
        __syncthreads();
    }
    if (t == 0) bsum[blockIdx.x] = red[0];
}

__global__ __launch_bounds__(256) void scan_phase2(
    const int* __restrict__ bsum, int* __restrict__ boff,
    int* __restrict__ rowptr, int nblk, int n) {
    __shared__ int sums[256];
    int t = threadIdx.x;
    int v = (t < nblk) ? bsum[t] : 0;
    int orig = v;
    sums[t] = v;
    __syncthreads();
    for (int off = 1; off < 256; off <<= 1) {
        int u = (t >= off) ? sums[t - off] : 0;
        __syncthreads();
        sums[t] += u;
        __syncthreads();
    }
    if (t < nblk) boff[t] = sums[t] - orig;
    if (t == nblk - 1) rowptr[n] = sums[t];
}

__global__ __launch_bounds__(256) void scan_phase3(
    const int* __restrict__ deg, const int* __restrict__ boff,
    int* __restrict__ rowptr, int n) {
    __shared__ int sums[256];
    int t = threadIdx.x;
    int i0 = blockIdx.x * 1024 + t * 4;
    int d0 = 0, d1 = 0, d2 = 0, d3 = 0;
    if (i0 + 3 < n) {
        int4 v = *reinterpret_cast<const int4*>(&deg[i0]);
        d0 = v.x - 1; d1 = v.y - 1; d2 = v.z - 1; d3 = v.w - 1;
    } else {
        if (i0 + 0 < n) d0 = deg[i0 + 0] - 1;
        if (i0 + 1 < n) d1 = deg[i0 + 1] - 1;
        if (i0 + 2 < n) d2 = deg[i0 + 2] - 1;
        if (i0 + 3 < n) d3 = deg[i0 + 3] - 1;
    }
    int ts = d0 + d1 + d2 + d3;
    sums[t] = ts;
    __syncthreads();
    for (int off = 1; off < 256; off <<= 1) {
        int u = (t >= off) ? sums[t - off] : 0;
        __syncthreads();
        sums[t] += u;
        __syncthreads();
    }
    int pre = boff[blockIdx.x] + sums[t] - ts;
    if (i0 + 0 < n) rowptr[i0 + 0] = pre; pre += d0;
    if (i0 + 1 < n) rowptr[i0 + 1] = pre; pre += d1;
    if (i0 + 2 < n) rowptr[i0 + 2] = pre; pre += d2;
    if (i0 + 3 < n) rowptr[i0 + 3] = pre;
}

__global__ void fill_kernel(const int* __restrict__ src, const int* __restrict__ dst,
                            const int* __restrict__ rowptr, int* __restrict__ cursor,
                            int* __restrict__ csr, int e) {
    int i = blockIdx.x * blockDim.x + threadIdx.x;
    int b = i * 4;
    if (b + 3 < e) {
        int4 s4 = *reinterpret_cast<const int4*>(&src[b]);
        int4 d4 = *reinterpret_cast<const int4*>(&dst[b]);
        int p;
        p = atomicAdd(&cursor[d4.x], 1); csr[rowptr[d4.x] + p] = s4.x;
        p = atomicAdd(&cursor[d4.y], 1); csr[rowptr[d4.y] + p] = s4.y;
        p = atomicAdd(&cursor[d4.z], 1); csr[rowptr[d4.z] + p] = s4.z;
        p = atomicAdd(&cursor[d4.w], 1); csr[rowptr[d4.w] + p] = s4.w;
    } else {
        for (int j = b; j < e; ++j) {
            int d = dst[j];
            int p = atomicAdd(&cursor[d], 1);
            csr[rowptr[d] + p] = src[j];
        }
    }
}

// ---------------- conversions ----------------

// W [K=256][N=256] f32 -> Wt [N][K] bf16 (transpose + convert)
__global__ __launch_bounds__(256) void transpose_cvt_kernel(
    const float* __restrict__ W, u16* __restrict__ Wt) {
    __shared__ float t[32][33];
    int bx = blockIdx.x * 32, by = blockIdx.y * 32;
    int tx = threadIdx.x & 31, ty = threadIdx.x >> 5;
#pragma unroll
    for (int i = 0; i < 32; i += 8)
        t[ty + i][tx] = W[(size_t)(bx + ty + i) * D + by + tx];
    __syncthreads();
#pragma unroll
    for (int i = 0; i < 32; i += 8)
        Wt[(size_t)(by + ty + i) * D + bx + tx] = f2bf(t[tx][ty + i]);
}

// ---------------- bf16 MFMA GEMM ----------------
// Bt: [256][256] bf16, Bt[n][k]. tile 128x128, BK=32, 4 waves (2x2).
// LDS layout: slot idx=(r*4+c), 16B each; content = global k-chunk
// (c ^ ((r>>1)&3)) of row r. Read with ksw = kg ^ ((l16>>1)&3).

// Variant A: A is bf16 (gload16 direct-to-LDS). epilogue: *dinv[row].
__global__ __launch_bounds__(256) void mfma_gemm(
    const u16* __restrict__ A, const u16* __restrict__ Bt,
    const float* __restrict__ dinv,
    u16* __restrict__ C, int M)
{
    __shared__ u16 As[128 * 32];
    __shared__ u16 Bs[128 * 32];
    const int tid = threadIdx.x;
    const int lane = tid & 63;
    const int wave = tid >> 6;
    const int wr = wave >> 1, wc = wave & 1;
    const int row0 = blockIdx.y * 128, col0 = blockIdx.x * 128;
    const int l16 = lane & 15, kg = lane >> 4;

    f32x4 acc[4][4] = {};

    for (int k0 = 0; k0 < D; k0 += 32) {
#pragma unroll
        for (int i = 0; i < 2; ++i) {
            int idx = i * 256 + tid;
            int r = idx >> 2, c = idx & 3;
            int csw = c ^ ((r >> 1) & 3);
            char* ldsbase_a = (char*)As + ((i * 256 + (tid & ~63)) << 4);
            char* ldsbase_b = (char*)Bs + ((i * 256 + (tid & ~63)) << 4);
            int grow = row0 + r; if (grow >= M) grow = M - 1;
            gload16(&A[(size_t)grow * D + k0 + csw * 8], ldsbase_a);
            gload16(&Bt[(size_t)(col0 + r) * D + k0 + csw * 8], ldsbase_b);
        }
        __syncthreads();
        bf16x8 af[4], bfr[4];
        int ksw = kg ^ ((l16 >> 1) & 3);
#pragma unroll
        for (int m = 0; m < 4; ++m)
            af[m] = *reinterpret_cast<const bf16x8*>(&As[(wr * 64 + m * 16 + l16) * 32 + ksw * 8]);
#pragma unroll
        for (int nn = 0; nn < 4; ++nn)
            bfr[nn] = *reinterpret_cast<const bf16x8*>(&Bs[(wc * 64 + nn * 16 + l16) * 32 + ksw * 8]);
#pragma unroll
        for (int m = 0; m < 4; ++m)
#pragma unroll
            for (int nn = 0; nn < 4; ++nn)
                acc[m][nn] = __builtin_amdgcn_mfma_f32_16x16x32_bf16(
                    af[m], bfr[nn], acc[m][nn], 0, 0, 0);
        __syncthreads();
    }

#pragma unroll
    for (int m = 0; m < 4; ++m) {
#pragma unroll
        for (int nn = 0; nn < 4; ++nn) {
            int gcol = col0 + wc * 64 + nn * 16 + l16;
#pragma unroll
            for (int j = 0; j < 4; ++j) {
                int grow = row0 + wr * 64 + m * 16 + kg * 4 + j;
                if (grow >= M) continue;
                C[(size_t)grow * D + gcol] = f2bf(acc[m][nn][j] * dinv[grow]);
            }
        }
    }
}

// Variant B: A is f32 (reg-stage + cvt_pk + ds_write). epilogue: relu(+bias).
__global__ __launch_bounds__(256) void mfma_gemm_f32a(
    const float* __restrict__ A, const u16* __restrict__ Bt,
    const float* __restrict__ bias,
    u16* __restrict__ C, int M)
{
    __shared__ u16 As[128 * 32];
    __shared__ u16 Bs[128 * 32];
    const int tid = threadIdx.x;
    const int lane = tid & 63;
    const int wave = tid >> 6;
    const int wr = wave >> 1, wc = wave & 1;
    const int row0 = blockIdx.y * 128, col0 = blockIdx.x * 128;
    const int l16 = lane & 15, kg = lane >> 4;

    f32x4 acc[4][4] = {};

    for (int k0 = 0; k0 < D; k0 += 32) {
        // B: gload16 direct
#pragma unroll
        for (int i = 0; i < 2; ++i) {
            int idx = i * 256 + tid;
            int r = idx >> 2, c = idx & 3;
            int csw = c ^ ((r >> 1) & 3);
            char* ldsbase_b = (char*)Bs + ((i * 256 + (tid & ~63)) << 4);
            gload16(&Bt[(size_t)(col0 + r) * D + k0 + csw * 8], ldsbase_b);
        }
        // A: f32 load x2 -> cvt_pk -> ds_write_b128, same swizzled slots
#pragma unroll
        for (int i = 0; i < 2; ++i) {
            int idx = i * 256 + tid;          // slot id 0..511
            int r = idx >> 2, c = idx & 3;
            int csw = c ^ ((r >> 1) & 3);
            int grow = row0 + r; if (grow >= M) grow = M - 1;
            const float* gp = &A[(size_t)grow * D + k0 + csw * 8];
            float4 v0 = *reinterpret_cast<const float4*>(gp);
            float4 v1 = *reinterpret_cast<const float4*>(gp + 4);
            uint4 w;
            w.x = cvtpk_bf16(v0.x, v0.y);
            w.y = cvtpk_bf16(v0.z, v0.w);
            w.z = cvtpk_bf16(v1.x, v1.y);
            w.w = cvtpk_bf16(v1.z, v1.w);
            *reinterpret_cast<uint4*>((char*)As + (idx << 4)) = w;
        }
        __syncthreads();
        bf16x8 af[4], bfr[4];
        int ksw = kg ^ ((l16 >> 1) & 3);
#pragma unroll
        for (int m = 0; m < 4; ++m)
            af[m] = *reinterpret_cast<const bf16x8*>(&As[(wr * 64 + m * 16 + l16) * 32 + ksw * 8]);
#pragma unroll
        for (int nn = 0; nn < 4; ++nn)
            bfr[nn] = *reinterpret_cast<const bf16x8*>(&Bs[(wc * 64 + nn * 16 + l16) * 32 + ksw * 8]);
#pragma unroll
        for (int m = 0; m < 4; ++m)
#pragma unroll
            for (int nn = 0; nn < 4; ++nn)
                acc[m][nn] = __builtin_amdgcn_mfma_f32_16x16x32_bf16(
                    af[m], bfr[nn], acc[m][nn], 0, 0, 0);
        __syncthreads();
    }

#pragma unroll
    for (int m = 0; m < 4; ++m) {
#pragma unroll
        for (int nn = 0; nn < 4; ++nn) {
            int gcol = col0 + wc * 64 + nn * 16 + l16;
#pragma unroll
            for (int j = 0; j < 4; ++j) {
                int grow = row0 + wr * 64 + m * 16 + kg * 4 + j;
                if (grow >= M) continue;
                C[(size_t)grow * D + gcol] = f2bf(fmaxf(acc[m][nn][j] + bias[gcol], 0.f));
            }
        }
    }
}

// ---------------- aggregation v4: forced-MLP asm load bursts ----------------
// out[d] = relu(dinv[d] * (hn[d] + sum_{s in in(d)} hn[s]) + bias[col])
// Half-wave per edge, lane loads 16B (8 cols). Per 16 edges: 8 inline-asm
// global_load_dwordx4 issued back-to-back (8 in flight), one vmcnt(0) drain,
// then accumulate. sched_barrier keeps consumers below the waitcnt (rule #18).
__global__ __launch_bounds__(256) void agg_kernel(
    const u16* __restrict__ hn, const int* __restrict__ rowptr,
    const int* __restrict__ csr, const float* __restrict__ dinv,
    const float* __restrict__ bias,
    u16* __restrict__ out_bf, float* __restrict__ out_f32, int n)
{
    int wave = threadIdx.x >> 6;
    int lane = threadIdx.x & 63;
    int node = blockIdx.x * 4 + wave;
    if (node >= n) return;
    int h = lane >> 5;          // half-wave id: edge parity
    int l5 = lane & 31;
    int c8 = l5 * 8;            // column base (8 bf16 = 16B per lane)

    float a[8] = {0.f, 0.f, 0.f, 0.f, 0.f, 0.f, 0.f, 0.f};

#define ACC8(vv) { \
    a[0] += bf2f((u16)(vv)[0]); a[1] += bf2f((u16)(vv)[1]); \
    a[2] += bf2f((u16)(vv)[2]); a[3] += bf2f((u16)(vv)[3]); \
    a[4] += bf2f((u16)(vv)[4]); a[5] += bf2f((u16)(vv)[5]); \
    a[6] += bf2f((u16)(vv)[6]); a[7] += bf2f((u16)(vv)[7]); }
#define ROWP(s) (&hn[(size_t)(s) * D + c8])

    if (h == 0) {
        bf16x8 v = *reinterpret_cast<const bf16x8*>(ROWP(node));
        ACC8(v);
    }

    int e0 = rowptr[node], e1 = rowptr[node + 1];
    for (int base = e0; base < e1; base += 64) {
        int bi = base + lane;
        int idx = (bi < e1) ? csr[bi] : 0;
        int cnt = e1 - base; if (cnt > 64) cnt = 64;
        int it = 0;
        for (; it + 16 <= cnt; it += 16) {
            int s0 = __shfl(idx, it + 0  + h);
            int s1 = __shfl(idx, it + 2  + h);
            int s2 = __shfl(idx, it + 4  + h);
            int s3 = __shfl(idx, it + 6  + h);
            int s4 = __shfl(idx, it + 8  + h);
            int s5 = __shfl(idx, it + 10 + h);
            int s6 = __shfl(idx, it + 12 + h);
            int s7 = __shfl(idx, it + 14 + h);
            bf16x8 v0 = gload_row(ROWP(s0));
            bf16x8 v1 = gload_row(ROWP(s1));
            bf16x8 v2 = gload_row(ROWP(s2));
            bf16x8 v3 = gload_row(ROWP(s3));
            bf16x8 v4 = gload_row(ROWP(s4));
            bf16x8 v5 = gload_row(ROWP(s5));
            bf16x8 v6 = gload_row(ROWP(s6));
            bf16x8 v7 = gload_row(ROWP(s7));
            asm volatile("s_waitcnt vmcnt(0)" ::: "memory");
            __builtin_amdgcn_sched_barrier(0);
            ACC8(v0); ACC8(v1); ACC8(v2); ACC8(v3);
            ACC8(v4); ACC8(v5); ACC8(v6); ACC8(v7);
        }
        for (; it + 8 <= cnt; it += 8) {
            int s0 = __shfl(idx, it + 0 + h);
            int s1 = __shfl(idx, it + 2 + h);
            int s2 = __shfl(idx, it + 4 + h);
            int s3 = __shfl(idx, it + 6 + h);
            bf16x8 v0 = gload_row(ROWP(s0));
            bf16x8 v1 = gload_row(ROWP(s1));
            bf16x8 v2 = gload_row(ROWP(s2));
            bf16x8 v3 = gload_row(ROWP(s3));
            asm volatile("s_waitcnt vmcnt(0)" ::: "memory");
            __builtin_amdgcn_sched_barrier(0);
            ACC8(v0); ACC8(v1); ACC8(v2); ACC8(v3);
        }
        for (; it + 2 <= cnt; it += 2) {
            int s0 = __shfl(idx, it + h);
            bf16x8 v0 = *reinterpret_cast<const bf16x8*>(ROWP(s0));
            ACC8(v0);
        }
        if (it < cnt) {
            int s0 = __shfl(idx, it);
            if (h == 0) {
                bf16x8 v0 = *reinterpret_cast<const bf16x8*>(ROWP(s0));
                ACC8(v0);
            }
        }
    }
#undef ACC8
#undef ROWP

#pragma unroll
    for (int j = 0; j < 8; ++j) a[j] += __shfl(a[j], lane ^ 32);

    if (h == 0) {
        float di = dinv[node];
#pragma unroll
        for (int j = 0; j < 8; ++j) a[j] = fmaxf(a[j] * di + bias[c8 + j], 0.f);
        if (out_bf) {
            bf16x8 o;
#pragma unroll
            for (int j = 0; j < 8; ++j) o[j] = (short)f2bf(a[j]);
            *reinterpret_cast<bf16x8*>(&out_bf[(size_t)node * D + c8]) = o;
        } else {
            float4 o0, o1;
            o0.x = a[0]; o0.y = a[1]; o0.z = a[2]; o0.w = a[3];
            o1.x = a[4]; o1.y = a[5]; o1.z = a[6]; o1.w = a[7];
            *reinterpret_cast<float4*>(&out_f32[(size_t)node * D + c8 + 0]) = o0;
            *reinterpret_cast<float4*>(&out_f32[(size_t)node * D + c8 + 4]) = o1;
        }
    }
}

// ---------------- launch ----------------

extern "C" void kernel_launch(void* const* d_in, const int* in_sizes, int n_in,
                              void* d_out, int out_size, void* d_ws, size_t ws_size,
                              hipStream_t stream) {
    const float* input  = (const float*)d_in[0];
    const int*   edge   = (const int*)d_in[1];
    const float* weight = (const float*)d_in[2];
    const float* bias   = (const float*)d_in[3];
    const float* conv_w = (const float*)d_in[4];
    const float* conv_b = (const float*)d_in[5];
    float* out = (float*)d_out;

    const int n = in_sizes[0] / D;     // 50000
    const int E = in_sizes[1] / 2;     // 800000
    const int* src = edge;
    const int* dst = edge + E;

    char* ws = (char*)d_ws;
    size_t off = 0;
    auto alloc = [&](size_t bytes) -> void* {
        void* p = ws + off;
        off = (off + bytes + 255) & ~(size_t)255;
        return p;
    };
    u16*   bufA   = (u16*)alloc((size_t)n * D * sizeof(u16));
    u16*   bufB   = (u16*)alloc((size_t)n * D * sizeof(u16));
    u16*   Wt     = (u16*)alloc((size_t)3 * D * D * sizeof(u16));
    int*   deg    = (int*)alloc((size_t)n * sizeof(int));
    int*   cursor = (int*)alloc((size_t)n * sizeof(int));
    float* dinv   = (float*)alloc((size_t)n * sizeof(float));
    int*   rowptr = (int*)alloc((size_t)(n + 1) * sizeof(int));
    int*   csr    = (int*)alloc((size_t)E * sizeof(int));
    int    nscan  = (n + 1023) / 1024;
    int*   bsum   = (int*)alloc((size_t)nscan * sizeof(int));
    int*   boff   = (int*)alloc((size_t)nscan * sizeof(int));

    int nb = (n + 255) / 256;
    int eb4 = (E / 4 + 255) / 256;
    init_kernel<<<nb, 256, 0, stream>>>(deg, cursor, n);
    hist_kernel<<<eb4, 256, 0, stream>>>(dst, deg, E);
    scan_phase1<<<nscan, 256, 0, stream>>>(deg, bsum, dinv, n);
    scan_phase2<<<1, 256, 0, stream>>>(bsum, boff, rowptr, nscan, n);
    scan_phase3<<<nscan, 256, 0, stream>>>(deg, boff, rowptr, n);
    fill_kernel<<<eb4, 256, 0, stream>>>(src, dst, rowptr, cursor, csr, E);

    dim3 tgrid(8, 8);
    transpose_cvt_kernel<<<tgrid, 256, 0, stream>>>(weight, Wt);
    transpose_cvt_kernel<<<tgrid, 256, 0, stream>>>(conv_w, Wt + D * D);
    transpose_cvt_kernel<<<tgrid, 256, 0, stream>>>(conv_w + D * D, Wt + 2 * D * D);

    dim3 ggrid(D / 128, (n + 127) / 128);
    // x1 = relu(input @ W + b)        -> bufA (bf16), fuses f32->bf16 cvt of input
    mfma_gemm_f32a<<<ggrid, 256, 0, stream>>>(input, Wt, bias, bufA, n);
    // hn = (x1 @ W0) * dinv[row]      -> bufB
    mfma_gemm<<<ggrid, 256, 0, stream>>>(bufA, Wt + D * D, dinv, bufB, n);
    // x2 = relu(dinv * agg(hn) + b0)  -> bufA
    agg_kernel<<<(n + 3) / 4, 256, 0, stream>>>(bufB, rowptr, csr, dinv, conv_b, bufA, nullptr, n);
    // hn2 = (x2 @ W1) * dinv[row]     -> bufB
    mfma_gemm<<<ggrid, 256, 0, stream>>>(bufA, Wt + 2 * D * D, dinv, bufB, n);
    // out = relu(dinv * agg(hn2) + b1) -> out (f32)
    agg_kernel<<<(n + 3) / 4, 256, 0, stream>>>(bufB, rowptr, csr, dinv, conv_b + D, nullptr, out, n);
}